// Round 9
// baseline (306.626 us; speedup 1.0000x reference)
//
#include <hip/hip_runtime.h>
#include <hip/hip_fp16.h>

#define NU 50000
#define NP 50000
#define NN 100000
#define NE 600000
#define H  128
#define O  16

typedef __attribute__((ext_vector_type(8))) _Float16 half8;
typedef __attribute__((ext_vector_type(4))) _Float16 h4v;
typedef __attribute__((ext_vector_type(4))) float f32x4;

// ---------------------------------------------------------------- fused prep:
// [0,75776)        : 2-term f16 weight decomposition (x16 scaled)
// [75776,+NN)      : zero cnt
// [+NN,+NN+8)      : zero epack pad
// [175784,+NU*16)  : user fp32 -> fp16 row-convert  (xU [NU][64])
// [+NU*16,+NP*32)  : prod fp32 -> fp16 pad-convert  (xP [NP][128])
__global__ void k_prep(const float* __restrict__ Wu, const float* __restrict__ Wp,
                       const float* __restrict__ W1, const float* __restrict__ W2,
                       const float* __restrict__ W3, const float* __restrict__ Wo,
                       const float* __restrict__ user, const float* __restrict__ prod,
                       __half* __restrict__ whU, __half* __restrict__ wlU,
                       __half* __restrict__ whP, __half* __restrict__ wlP,
                       __half* __restrict__ wh1, __half* __restrict__ wl1,
                       __half* __restrict__ wh2, __half* __restrict__ wl2,
                       __half* __restrict__ wh3, __half* __restrict__ wl3,
                       __half* __restrict__ whO, __half* __restrict__ wlO,
                       __half* __restrict__ xU, __half* __restrict__ xP,
                       int* __restrict__ cnt, int2* __restrict__ epack) {
    int idx = blockIdx.x * blockDim.x + threadIdx.x;
    if (idx >= 175784) {
        int i = idx - 175784;
        if (i < NU * 16) {
            int e = i * 4;
            float4 v = *(const float4*)(user + e);
            __half2 a = __floats2half2_rn(v.x, v.y);
            __half2 b = __floats2half2_rn(v.z, v.w);
            uint2 o; o.x = *(unsigned*)&a; o.y = *(unsigned*)&b;
            *(uint2*)(xU + e) = o;
        } else {
            int q = i - NU * 16;
            if (q >= NP * 32) return;
            int row = q >> 5, kq = (q & 31) * 4;
            float4 v;
            if (kq < 100) v = *(const float4*)(prod + row * 100 + kq);
            else { v.x = 0.f; v.y = 0.f; v.z = 0.f; v.w = 0.f; }
            __half2 a = __floats2half2_rn(v.x, v.y);
            __half2 b = __floats2half2_rn(v.z, v.w);
            uint2 o; o.x = *(unsigned*)&a; o.y = *(unsigned*)&b;
            *(uint2*)(xP + (size_t)row * 128 + kq) = o;
        }
        return;
    }
    if (idx >= 75776) {
        int i = idx - 75776;
        if (i < NN) cnt[i] = 0;
        else if (i < NN + 8) { int2 z; z.x = 0; z.y = 0; epack[NE + (i - NN)] = z; }
        return;
    }
    const float* W; __half *Wh, *Wl; int K, KPAD, NC;
    if      (idx <  8192) {              W = Wu; Wh = whU; Wl = wlU; K =  64; KPAD =  64; NC = 128; }
    else if (idx < 24576) { idx -=  8192; W = Wp; Wh = whP; Wl = wlP; K = 100; KPAD = 128; NC = 128; }
    else if (idx < 40960) { idx -= 24576; W = W1; Wh = wh1; Wl = wl1; K = 128; KPAD = 128; NC = 128; }
    else if (idx < 57344) { idx -= 40960; W = W2; Wh = wh2; Wl = wl2; K = 128; KPAD = 128; NC = 128; }
    else if (idx < 73728) { idx -= 57344; W = W3; Wh = wh3; Wl = wl3; K = 128; KPAD = 128; NC = 128; }
    else                  { idx -= 73728; W = Wo; Wh = whO; Wl = wlO; K = 128; KPAD = 128; NC =  16; }
    int n = idx / KPAD, k = idx - n * KPAD;
    float x = (k < K) ? W[k * NC + n] * 16.0f : 0.0f;
    __half h = __float2half_rn(x);
    __half l = __float2half_rn(x - __half2float(h));
    Wh[idx] = h; Wl[idx] = l;
}

// ---------------------------------------------------------------- degree count + rank
__global__ void k_count(const int* __restrict__ dst, int* __restrict__ cnt,
                        int* __restrict__ rank, int E) {
    int e = blockIdx.x * blockDim.x + threadIdx.x;
    if (e < E) rank[e] = atomicAdd(&cnt[dst[e]], 1);
}

// ---------------------------------------------------------------- exclusive scan
#define SCAN_TPB 256
#define SCAN_VPT 4
#define SCAN_CHUNK (SCAN_TPB * SCAN_VPT)   // 1024 -> consumers use >>10

__global__ void k_scan1(const int* __restrict__ in, int* __restrict__ out,
                        int* __restrict__ bsums, float* __restrict__ dinv, int n) {
    __shared__ int sh[SCAN_TPB];
    int t = threadIdx.x, b = blockIdx.x;
    int base = b * SCAN_CHUNK + t * SCAN_VPT;
    int v[SCAN_VPT]; int s = 0;
#pragma unroll
    for (int i = 0; i < SCAN_VPT; i++) {
        int idx = base + i;
        v[i] = (idx < n) ? in[idx] : 0;
        if (idx < n) dinv[idx] = rsqrtf((float)(v[i] + 1));
        s += v[i];
    }
    sh[t] = s; __syncthreads();
    for (int off = 1; off < SCAN_TPB; off <<= 1) {
        int x = (t >= off) ? sh[t - off] : 0;
        __syncthreads();
        sh[t] += x;
        __syncthreads();
    }
    int run = (t > 0) ? sh[t - 1] : 0;
    if (t == SCAN_TPB - 1) bsums[b] = sh[t];
#pragma unroll
    for (int i = 0; i < SCAN_VPT; i++) {
        int idx = base + i;
        if (idx < n) out[idx] = run;
        run += v[i];
    }
}

__global__ void k_scan2(int* __restrict__ bsums, int nb) {
    __shared__ int sh[128];
    int t = threadIdx.x;
    int v = (t < nb) ? bsums[t] : 0;
    sh[t] = v; __syncthreads();
    for (int off = 1; off < 128; off <<= 1) {
        int x = (t >= off) ? sh[t - off] : 0;
        __syncthreads();
        sh[t] += x;
        __syncthreads();
    }
    if (t < nb) bsums[t] = sh[t] - v;
}

// ---------------------------------------------------------------- register-resident MFMA GEMM
template <typename AT, int K, int KPAD, int NI, int MI, int NOUT, bool BIAS, bool F32OUT>
__device__ __forceinline__
void gemm_body(const AT* __restrict__ X,
               const __half* __restrict__ Wh, const __half* __restrict__ Wl,
               const float* __restrict__ bias, void* __restrict__ Cout,
               int M, int orow0, int vb) {
    constexpr int KS = KPAD / 32;
    constexpr int CSPLIT = NOUT / (16 * MI);
    const int tid  = threadIdx.x;
    const int wid  = tid >> 6, lane = tid & 63;
    const int lm   = lane & 15, q = lane >> 4;
    const int gw   = vb * 4 + wid;
    const int tile = gw / CSPLIT;
    const int c0   = (gw % CSPLIT) * (MI * 16);
    const int NT   = (M + NI * 16 - 1) / (NI * 16);
    if (tile >= NT) return;
    const int n0 = tile * (NI * 16);

    half8 wh[MI][KS], wl[MI][KS];
#pragma unroll
    for (int mi = 0; mi < MI; mi++)
#pragma unroll
        for (int ks = 0; ks < KS; ks++) {
            const size_t b = (size_t)(c0 + mi * 16 + lm) * KPAD + ks * 32 + q * 8;
            wh[mi][ks] = *(const half8*)&Wh[b];
            wl[mi][ks] = *(const half8*)&Wl[b];
        }

    f32x4 acc[NI][MI];
#pragma unroll
    for (int ni = 0; ni < NI; ni++)
#pragma unroll
        for (int mi = 0; mi < MI; mi++) acc[ni][mi] = (f32x4)0.0f;

#pragma unroll
    for (int ni = 0; ni < NI; ni++) {
        const int node = n0 + ni * 16 + lm;
        half8 xf[KS];
        if (node < M) {
#pragma unroll
            for (int ks = 0; ks < KS; ks++)
                xf[ks] = *(const half8*)((const __half*)X + (size_t)node * KPAD + ks * 32 + q * 8);
        } else {
#pragma unroll
            for (int ks = 0; ks < KS; ks++)
#pragma unroll
                for (int j = 0; j < 8; j++) xf[ks][j] = (_Float16)0.0f;
        }
#pragma unroll
        for (int ks = 0; ks < KS; ks++)
#pragma unroll
            for (int mi = 0; mi < MI; mi++) {
                acc[ni][mi] = __builtin_amdgcn_mfma_f32_16x16x32_f16(wh[mi][ks], xf[ks], acc[ni][mi], 0, 0, 0);
                acc[ni][mi] = __builtin_amdgcn_mfma_f32_16x16x32_f16(wl[mi][ks], xf[ks], acc[ni][mi], 0, 0, 0);
            }
    }

#pragma unroll
    for (int ni = 0; ni < NI; ni++) {
        const int node = n0 + ni * 16 + lm;
        if (node >= M) continue;
#pragma unroll
        for (int mi = 0; mi < MI; mi++) {
            const int cb = c0 + mi * 16 + q * 4;
            float4 bv = BIAS ? *(const float4*)&bias[cb] : make_float4(0.f, 0.f, 0.f, 0.f);
            float v0 = fmaf(acc[ni][mi][0], 0.0625f, bv.x);
            float v1 = fmaf(acc[ni][mi][1], 0.0625f, bv.y);
            float v2 = fmaf(acc[ni][mi][2], 0.0625f, bv.z);
            float v3 = fmaf(acc[ni][mi][3], 0.0625f, bv.w);
            if constexpr (F32OUT) {
                *(float4*)((float*)Cout + (size_t)(orow0 + node) * NOUT + cb) =
                    make_float4(v0, v1, v2, v3);
            } else {
                __half2 h0 = __floats2half2_rn(v0, v1);
                __half2 h1 = __floats2half2_rn(v2, v3);
                uint2 o; o.x = *(unsigned*)&h0; o.y = *(unsigned*)&h1;
                *(uint2*)((__half*)Cout + (size_t)(orow0 + node) * NOUT + cb) = o;
            }
        }
    }
}

template <typename AT, int K, int KPAD, int NI, int MI, int NOUT, bool BIAS, bool F32OUT>
__launch_bounds__(256)
__global__ void k_gemm_reg(const AT* __restrict__ X,
                           const __half* __restrict__ Wh, const __half* __restrict__ Wl,
                           const float* __restrict__ bias, void* __restrict__ Cout,
                           int M, int orow0) {
    gemm_body<AT, K, KPAD, NI, MI, NOUT, BIAS, F32OUT>(X, Wh, Wl, bias, Cout, M, orow0, blockIdx.x);
}

// ---------------------------------------------------------------- fill + input transforms (one launch)
// blocks [0,782): user gemm; [782,2345): prod gemm; [2345,2345+2344): CSR fill
#define BLK_U 782
#define BLK_P 1563
#define BLK_F 2344
__launch_bounds__(256)
__global__ void k_fill_inputs(const int* __restrict__ src, const int* __restrict__ dst,
                              const int* __restrict__ offs, const int* __restrict__ bsums,
                              const int* __restrict__ rank, const float* __restrict__ dinv,
                              int2* __restrict__ epack,
                              const __half* __restrict__ xU, const __half* __restrict__ xP,
                              const __half* __restrict__ whU, const __half* __restrict__ wlU,
                              const __half* __restrict__ whP, const __half* __restrict__ wlP,
                              const float* __restrict__ bu, const float* __restrict__ bp,
                              void* __restrict__ xA) {
    const int b = blockIdx.x;
    if (b < BLK_U) {
        gemm_body<__half,  64,  64, 2, 4, 128, true, false>(xU, whU, wlU, bu, xA, NU, 0, b);
    } else if (b < BLK_U + BLK_P) {
        gemm_body<__half, 128, 128, 2, 2, 128, true, false>(xP, whP, wlP, bp, xA, NP, NU, b - BLK_U);
    } else {
        int e = (b - BLK_U - BLK_P) * 256 + threadIdx.x;
        if (e < NE) {
            int s = src[e], d = dst[e];
            int p = offs[d] + bsums[d >> 10] + rank[e];
            int2 r;
            r.x = s;
            r.y = __float_as_int(dinv[s] * dinv[d]);
            epack[p] = r;
        }
    }
}

// ---------------------------------------------------------------- FUSED aggregate + GEMM
// Block = 16 output nodes. Phase 1: each wave aggregates 4 nodes (the MEASURED
// 40us gather structure: full 256B rows, 8B lanes, 2 rows/gather-instr, 8-edge
// predicated batches) -> relu(agg+bias_in) -> fp16 LDS tile z[16][136] (pad 8
// halves => 2-way bank aliasing = free). Phase 2: barrier; z @ W via MFMA
// (W frags loaded pre-barrier, L2-hot) -> write g_next. Eliminates the 25.6MB
// x' materialization + the next gemm's 25.6MB re-read per layer.
template <int NOUT, bool F32OUT>
__launch_bounds__(256)
__global__ void k_agg_gemm(const __half* __restrict__ y, const int* __restrict__ offs,
                           const int* __restrict__ bsums, const int2* __restrict__ epack,
                           const float* __restrict__ dinv, const float* __restrict__ bias_in,
                           const __half* __restrict__ Wh, const __half* __restrict__ Wl,
                           const float* __restrict__ bias_out, void* __restrict__ Cout) {
    constexpr int LH = 136;                    // 128 + 8 pad halves
    constexpr int MI = (NOUT == 128) ? 2 : 1;
    __shared__ __half z[16][LH];
    const int t   = blockIdx.x;
    const int wid = threadIdx.x >> 6;
    const int l   = threadIdx.x & 63;
    const int h   = l >> 5, j = l & 31;
    const h4v* y4 = (const h4v*)y;

    // ---- phase 1: aggregate nodes t*16 + wid*4 + {0..3} ----
#pragma unroll
    for (int n = 0; n < 4; n++) {
        const int row  = wid * 4 + n;
        const int node = __builtin_amdgcn_readfirstlane(t * 16 + row);
        int e0 = offs[node] + bsums[node >> 10];
        int e1 = (node + 1 < NN) ? (offs[node + 1] + bsums[(node + 1) >> 10]) : NE;
        e0 = __builtin_amdgcn_readfirstlane(e0);
        e1 = __builtin_amdgcn_readfirstlane(e1);

        const float di2 = dinv[node] * dinv[node];
        h4v sv = y4[(size_t)node * 32 + j];
        float4 bv = *(const float4*)&bias_in[4 * j];

        f32x4 acc0 = (f32x4)0.f, acc1 = (f32x4)0.f, acc2 = (f32x4)0.f, acc3 = (f32x4)0.f;
        for (int e = e0; e < e1; e += 8) {
            const int eb = e + 4 * h;
            const int2* pe = epack + eb;
            int2 p0 = pe[0];
            int2 p1 = pe[1];
            int2 p2 = pe[2];
            int2 p3 = pe[3];
            float w0 = (eb + 0 < e1) ? __int_as_float(p0.y) : 0.f;
            float w1 = (eb + 1 < e1) ? __int_as_float(p1.y) : 0.f;
            float w2 = (eb + 2 < e1) ? __int_as_float(p2.y) : 0.f;
            float w3 = (eb + 3 < e1) ? __int_as_float(p3.y) : 0.f;
            h4v v0 = y4[(size_t)p0.x * 32 + j];
            h4v v1 = y4[(size_t)p1.x * 32 + j];
            h4v v2 = y4[(size_t)p2.x * 32 + j];
            h4v v3 = y4[(size_t)p3.x * 32 + j];
            acc0[0] = fmaf((float)v0[0], w0, acc0[0]); acc0[1] = fmaf((float)v0[1], w0, acc0[1]);
            acc0[2] = fmaf((float)v0[2], w0, acc0[2]); acc0[3] = fmaf((float)v0[3], w0, acc0[3]);
            acc1[0] = fmaf((float)v1[0], w1, acc1[0]); acc1[1] = fmaf((float)v1[1], w1, acc1[1]);
            acc1[2] = fmaf((float)v1[2], w1, acc1[2]); acc1[3] = fmaf((float)v1[3], w1, acc1[3]);
            acc2[0] = fmaf((float)v2[0], w2, acc2[0]); acc2[1] = fmaf((float)v2[1], w2, acc2[1]);
            acc2[2] = fmaf((float)v2[2], w2, acc2[2]); acc2[3] = fmaf((float)v2[3], w2, acc2[3]);
            acc3[0] = fmaf((float)v3[0], w3, acc3[0]); acc3[1] = fmaf((float)v3[1], w3, acc3[1]);
            acc3[2] = fmaf((float)v3[2], w3, acc3[2]); acc3[3] = fmaf((float)v3[3], w3, acc3[3]);
        }

        f32x4 s = (acc0 + acc1) + (acc2 + acc3);
        float t0 = s[0] + __shfl_xor(s[0], 32, 64);
        float t1 = s[1] + __shfl_xor(s[1], 32, 64);
        float t2 = s[2] + __shfl_xor(s[2], 32, 64);
        float t3 = s[3] + __shfl_xor(s[3], 32, 64);

        float r0 = fmaf((float)sv[0], di2, t0) + bv.x;
        float r1 = fmaf((float)sv[1], di2, t1) + bv.y;
        float r2 = fmaf((float)sv[2], di2, t2) + bv.z;
        float r3 = fmaf((float)sv[3], di2, t3) + bv.w;
        if (l < 32) {
            __half2 ha = __floats2half2_rn(fmaxf(r0, 0.f), fmaxf(r1, 0.f));
            __half2 hb = __floats2half2_rn(fmaxf(r2, 0.f), fmaxf(r3, 0.f));
            uint2 o; o.x = *(unsigned*)&ha; o.y = *(unsigned*)&hb;
            *(uint2*)&z[row][4 * j] = o;
        }
    }

    // ---- W fragments (L2-hot), issued before the barrier ----
    const int lm = l & 15, q = l >> 4;
    const int c0 = (NOUT == 128) ? wid * 32 : 0;
    half8 wh[MI][4], wl[MI][4];
    const bool active = (NOUT == 128) || (wid == 0);
    if (active) {
#pragma unroll
        for (int mi = 0; mi < MI; mi++)
#pragma unroll
            for (int ks = 0; ks < 4; ks++) {
                const size_t b = (size_t)(c0 + mi * 16 + lm) * 128 + ks * 32 + q * 8;
                wh[mi][ks] = *(const half8*)&Wh[b];
                wl[mi][ks] = *(const half8*)&Wl[b];
            }
    }
    __syncthreads();
    if (!active) return;

    // ---- phase 2: z[16][128] @ W -> [16][NOUT] ----
    half8 xf[4];
#pragma unroll
    for (int ks = 0; ks < 4; ks++)
        xf[ks] = *(const half8*)&z[lm][ks * 32 + q * 8];

    f32x4 acc[MI];
#pragma unroll
    for (int mi = 0; mi < MI; mi++) acc[mi] = (f32x4)0.0f;
#pragma unroll
    for (int ks = 0; ks < 4; ks++)
#pragma unroll
        for (int mi = 0; mi < MI; mi++) {
            acc[mi] = __builtin_amdgcn_mfma_f32_16x16x32_f16(wh[mi][ks], xf[ks], acc[mi], 0, 0, 0);
            acc[mi] = __builtin_amdgcn_mfma_f32_16x16x32_f16(wl[mi][ks], xf[ks], acc[mi], 0, 0, 0);
        }

    const int node = t * 16 + lm;
#pragma unroll
    for (int mi = 0; mi < MI; mi++) {
        const int cb = c0 + mi * 16 + q * 4;
        float4 bv = F32OUT ? *(const float4*)&bias_out[cb] : make_float4(0.f, 0.f, 0.f, 0.f);
        float v0 = fmaf(acc[mi][0], 0.0625f, bv.x);
        float v1 = fmaf(acc[mi][1], 0.0625f, bv.y);
        float v2 = fmaf(acc[mi][2], 0.0625f, bv.z);
        float v3 = fmaf(acc[mi][3], 0.0625f, bv.w);
        if constexpr (F32OUT) {
            *(float4*)((float*)Cout + (size_t)node * NOUT + cb) = make_float4(v0, v1, v2, v3);
        } else {
            __half2 h0 = __floats2half2_rn(v0, v1);
            __half2 h1 = __floats2half2_rn(v2, v3);
            uint2 o; o.x = *(unsigned*)&h0; o.y = *(unsigned*)&h1;
            *(uint2*)((__half*)Cout + (size_t)node * NOUT + cb) = o;
        }
    }
}

// ---------------------------------------------------------------- launch
extern "C" void kernel_launch(void* const* d_in, const int* in_sizes, int n_in,
                              void* d_out, int out_size, void* d_ws, size_t ws_size,
                              hipStream_t stream) {
    const float* user = (const float*)d_in[0];
    const float* prod = (const float*)d_in[1];
    const int*   eidx = (const int*)  d_in[2];
    const int*   edst = eidx + NE;
    const int*   esrc = eidx;
    const float* Wu = (const float*)d_in[3];
    const float* bu = (const float*)d_in[4];
    const float* Wp = (const float*)d_in[5];
    const float* bp = (const float*)d_in[6];
    const float* W1 = (const float*)d_in[7];
    const float* b1 = (const float*)d_in[8];
    const float* W2 = (const float*)d_in[9];
    const float* b2 = (const float*)d_in[10];
    const float* W3 = (const float*)d_in[11];
    const float* b3 = (const float*)d_in[12];
    const float* Wo = (const float*)d_in[13];
    const float* bo = (const float*)d_in[14];
    float* out = (float*)d_out;

    char* ws = (char*)d_ws;
    size_t p = 0;
    auto alloc = [&](size_t bytes) -> void* {
        void* r = ws + p;
        p += (bytes + 255) & ~(size_t)255;
        return r;
    };
    __half* xA   = (__half*)alloc((size_t)NN * H * 2);
    __half* xB   = (__half*)alloc((size_t)NN * H * 2);
    __half* xU   = (__half*)alloc((size_t)NU * 64 * 2);
    __half* xP   = (__half*)alloc((size_t)NP * 128 * 2);
    int*   cnt   = (int*)  alloc((size_t)NN * 4);
    int*   rank  = (int*)  alloc((size_t)NE * 4);
    int*   offs  = (int*)  alloc((size_t)(NN + 1) * 4);
    float* dinv  = (float*)alloc((size_t)NN * 4);
    int2*  epack = (int2*) alloc((size_t)(NE + 8) * 8);
    int*   bsums = (int*)  alloc(128 * 4);
    __half* whU = (__half*)alloc(128 * 64 * 2);
    __half* wlU = (__half*)alloc(128 * 64 * 2);
    __half* whP = (__half*)alloc(128 * 128 * 2);
    __half* wlP = (__half*)alloc(128 * 128 * 2);
    __half* wh1 = (__half*)alloc(128 * 128 * 2);
    __half* wl1 = (__half*)alloc(128 * 128 * 2);
    __half* wh2 = (__half*)alloc(128 * 128 * 2);
    __half* wl2 = (__half*)alloc(128 * 128 * 2);
    __half* wh3 = (__half*)alloc(128 * 128 * 2);
    __half* wl3 = (__half*)alloc(128 * 128 * 2);
    __half* whO = (__half*)alloc(16 * 128 * 2);
    __half* wlO = (__half*)alloc(16 * 128 * 2);

    const int NBLK = (NN + SCAN_CHUNK - 1) / SCAN_CHUNK;   // 98

    // prep (weights + cnt + epack pad + fp16 input conversion)
    {
        const int total = 175784 + NU * 16 + NP * 32;
        k_prep<<<(total + 255) / 256, 256, 0, stream>>>(
            Wu, Wp, W1, W2, W3, Wo, user, prod,
            whU, wlU, whP, wlP, wh1, wl1, wh2, wl2, wh3, wl3, whO, wlO,
            xU, xP, cnt, epack);
    }

    // graph structure
    k_count<<<(NE + 255) / 256, 256, 0, stream>>>(edst, cnt, rank, NE);
    k_scan1<<<NBLK, SCAN_TPB, 0, stream>>>(cnt, offs, bsums, dinv, NN);
    k_scan2<<<1, 128, 0, stream>>>(bsums, NBLK);

    // CSR fill + user/prod input transforms (one launch, block-range split)
    k_fill_inputs<<<BLK_U + BLK_P + BLK_F, 256, 0, stream>>>(
        esrc, edst, offs, bsums, rank, dinv, epack,
        xU, xP, whU, wlU, whP, wlP, bu, bp, xA);

    // layer 1 gemm: g1 = x0 @ W1 -> xB
    const int blkG = (1563 * 2 + 3) / 4;   // 782
    k_gemm_reg<__half, 128, 128, 4, 4, 128, false, false><<<blkG, 256, 0, stream>>>(xA, wh1, wl1, nullptr, xB, NN, 0);

    // fused layers: g2 = relu(Agg(g1)+b1) @ W2 ; g3 = relu(Agg(g2)+b2) @ W3 ;
    // out = relu(Agg(g3)+b3) @ Wo + bo
    const int blkF = NN / 16;              // 6250
    k_agg_gemm<128, false><<<blkF, 256, 0, stream>>>(xB, offs, bsums, epack, dinv, b1, wh2, wl2, nullptr, xA);
    k_agg_gemm<128, false><<<blkF, 256, 0, stream>>>(xA, offs, bsums, epack, dinv, b2, wh3, wl3, nullptr, xB);
    k_agg_gemm<16,  true ><<<blkF, 256, 0, stream>>>(xB, offs, bsums, epack, dinv, b3, whO, wlO, bo, out);
}

// Round 10
// 291.538 us; speedup vs baseline: 1.0518x; 1.0518x over previous
//
#include <hip/hip_runtime.h>
#include <hip/hip_fp16.h>

#define NU 50000
#define NP 50000
#define NN 100000
#define NE 600000
#define H  128
#define O  16

typedef __attribute__((ext_vector_type(8))) _Float16 half8;
typedef __attribute__((ext_vector_type(4))) _Float16 h4v;
typedef __attribute__((ext_vector_type(4))) float f32x4;

// ---------------------------------------------------------------- fused prep:
// [0,75776)        : 2-term f16 weight decomposition (x16 scaled)
// [75776,+NN)      : zero cnt
// [+NN,+NN+8)      : zero epack pad
// [175784,+NU*16)  : user fp32 -> fp16 row-convert  (xU [NU][64])
// [+NU*16,+NP*32)  : prod fp32 -> fp16 pad-convert  (xP [NP][128])
__global__ void k_prep(const float* __restrict__ Wu, const float* __restrict__ Wp,
                       const float* __restrict__ W1, const float* __restrict__ W2,
                       const float* __restrict__ W3, const float* __restrict__ Wo,
                       const float* __restrict__ user, const float* __restrict__ prod,
                       __half* __restrict__ whU, __half* __restrict__ wlU,
                       __half* __restrict__ whP, __half* __restrict__ wlP,
                       __half* __restrict__ wh1, __half* __restrict__ wl1,
                       __half* __restrict__ wh2, __half* __restrict__ wl2,
                       __half* __restrict__ wh3, __half* __restrict__ wl3,
                       __half* __restrict__ whO, __half* __restrict__ wlO,
                       __half* __restrict__ xU, __half* __restrict__ xP,
                       int* __restrict__ cnt, int2* __restrict__ epack) {
    int idx = blockIdx.x * blockDim.x + threadIdx.x;
    if (idx >= 175784) {
        int i = idx - 175784;
        if (i < NU * 16) {
            int e = i * 4;
            float4 v = *(const float4*)(user + e);
            __half2 a = __floats2half2_rn(v.x, v.y);
            __half2 b = __floats2half2_rn(v.z, v.w);
            uint2 o; o.x = *(unsigned*)&a; o.y = *(unsigned*)&b;
            *(uint2*)(xU + e) = o;
        } else {
            int q = i - NU * 16;
            if (q >= NP * 32) return;
            int row = q >> 5, kq = (q & 31) * 4;
            float4 v;
            if (kq < 100) v = *(const float4*)(prod + row * 100 + kq);
            else { v.x = 0.f; v.y = 0.f; v.z = 0.f; v.w = 0.f; }
            __half2 a = __floats2half2_rn(v.x, v.y);
            __half2 b = __floats2half2_rn(v.z, v.w);
            uint2 o; o.x = *(unsigned*)&a; o.y = *(unsigned*)&b;
            *(uint2*)(xP + (size_t)row * 128 + kq) = o;
        }
        return;
    }
    if (idx >= 75776) {
        int i = idx - 75776;
        if (i < NN) cnt[i] = 0;
        else if (i < NN + 8) { int2 z; z.x = 0; z.y = 0; epack[NE + (i - NN)] = z; }
        return;
    }
    const float* W; __half *Wh, *Wl; int K, KPAD, NC;
    if      (idx <  8192) {              W = Wu; Wh = whU; Wl = wlU; K =  64; KPAD =  64; NC = 128; }
    else if (idx < 24576) { idx -=  8192; W = Wp; Wh = whP; Wl = wlP; K = 100; KPAD = 128; NC = 128; }
    else if (idx < 40960) { idx -= 24576; W = W1; Wh = wh1; Wl = wl1; K = 128; KPAD = 128; NC = 128; }
    else if (idx < 57344) { idx -= 40960; W = W2; Wh = wh2; Wl = wl2; K = 128; KPAD = 128; NC = 128; }
    else if (idx < 73728) { idx -= 57344; W = W3; Wh = wh3; Wl = wl3; K = 128; KPAD = 128; NC = 128; }
    else                  { idx -= 73728; W = Wo; Wh = whO; Wl = wlO; K = 128; KPAD = 128; NC =  16; }
    int n = idx / KPAD, k = idx - n * KPAD;
    float x = (k < K) ? W[k * NC + n] * 16.0f : 0.0f;
    __half h = __float2half_rn(x);
    __half l = __float2half_rn(x - __half2float(h));
    Wh[idx] = h; Wl[idx] = l;
}

// ---------------------------------------------------------------- degree count + rank
__global__ void k_count(const int* __restrict__ dst, int* __restrict__ cnt,
                        int* __restrict__ rank, int E) {
    int e = blockIdx.x * blockDim.x + threadIdx.x;
    if (e < E) rank[e] = atomicAdd(&cnt[dst[e]], 1);
}

// ---------------------------------------------------------------- exclusive scan
#define SCAN_TPB 256
#define SCAN_VPT 4
#define SCAN_CHUNK (SCAN_TPB * SCAN_VPT)   // 1024 -> consumers use >>10

__global__ void k_scan1(const int* __restrict__ in, int* __restrict__ out,
                        int* __restrict__ bsums, float* __restrict__ dinv, int n) {
    __shared__ int sh[SCAN_TPB];
    int t = threadIdx.x, b = blockIdx.x;
    int base = b * SCAN_CHUNK + t * SCAN_VPT;
    int v[SCAN_VPT]; int s = 0;
#pragma unroll
    for (int i = 0; i < SCAN_VPT; i++) {
        int idx = base + i;
        v[i] = (idx < n) ? in[idx] : 0;
        if (idx < n) dinv[idx] = rsqrtf((float)(v[i] + 1));
        s += v[i];
    }
    sh[t] = s; __syncthreads();
    for (int off = 1; off < SCAN_TPB; off <<= 1) {
        int x = (t >= off) ? sh[t - off] : 0;
        __syncthreads();
        sh[t] += x;
        __syncthreads();
    }
    int run = (t > 0) ? sh[t - 1] : 0;
    if (t == SCAN_TPB - 1) bsums[b] = sh[t];
#pragma unroll
    for (int i = 0; i < SCAN_VPT; i++) {
        int idx = base + i;
        if (idx < n) out[idx] = run;
        run += v[i];
    }
}

__global__ void k_scan2(int* __restrict__ bsums, int nb) {
    __shared__ int sh[128];
    int t = threadIdx.x;
    int v = (t < nb) ? bsums[t] : 0;
    sh[t] = v; __syncthreads();
    for (int off = 1; off < 128; off <<= 1) {
        int x = (t >= off) ? sh[t - off] : 0;
        __syncthreads();
        sh[t] += x;
        __syncthreads();
    }
    if (t < nb) bsums[t] = sh[t] - v;
}

// ---------------------------------------------------------------- register-resident MFMA GEMM
template <typename AT, int K, int KPAD, int NI, int MI, int NOUT, bool BIAS, bool F32OUT>
__device__ __forceinline__
void gemm_body(const AT* __restrict__ X,
               const __half* __restrict__ Wh, const __half* __restrict__ Wl,
               const float* __restrict__ bias, void* __restrict__ Cout,
               int M, int orow0, int vb) {
    constexpr int KS = KPAD / 32;
    constexpr int CSPLIT = NOUT / (16 * MI);
    const int tid  = threadIdx.x;
    const int wid  = tid >> 6, lane = tid & 63;
    const int lm   = lane & 15, q = lane >> 4;
    const int gw   = vb * 4 + wid;
    const int tile = gw / CSPLIT;
    const int c0   = (gw % CSPLIT) * (MI * 16);
    const int NT   = (M + NI * 16 - 1) / (NI * 16);
    if (tile >= NT) return;
    const int n0 = tile * (NI * 16);

    half8 wh[MI][KS], wl[MI][KS];
#pragma unroll
    for (int mi = 0; mi < MI; mi++)
#pragma unroll
        for (int ks = 0; ks < KS; ks++) {
            const size_t b = (size_t)(c0 + mi * 16 + lm) * KPAD + ks * 32 + q * 8;
            wh[mi][ks] = *(const half8*)&Wh[b];
            wl[mi][ks] = *(const half8*)&Wl[b];
        }

    f32x4 acc[NI][MI];
#pragma unroll
    for (int ni = 0; ni < NI; ni++)
#pragma unroll
        for (int mi = 0; mi < MI; mi++) acc[ni][mi] = (f32x4)0.0f;

#pragma unroll
    for (int ni = 0; ni < NI; ni++) {
        const int node = n0 + ni * 16 + lm;
        half8 xf[KS];
        if (node < M) {
#pragma unroll
            for (int ks = 0; ks < KS; ks++)
                xf[ks] = *(const half8*)((const __half*)X + (size_t)node * KPAD + ks * 32 + q * 8);
        } else {
#pragma unroll
            for (int ks = 0; ks < KS; ks++)
#pragma unroll
                for (int j = 0; j < 8; j++) xf[ks][j] = (_Float16)0.0f;
        }
#pragma unroll
        for (int ks = 0; ks < KS; ks++)
#pragma unroll
            for (int mi = 0; mi < MI; mi++) {
                acc[ni][mi] = __builtin_amdgcn_mfma_f32_16x16x32_f16(wh[mi][ks], xf[ks], acc[ni][mi], 0, 0, 0);
                acc[ni][mi] = __builtin_amdgcn_mfma_f32_16x16x32_f16(wl[mi][ks], xf[ks], acc[ni][mi], 0, 0, 0);
            }
    }

#pragma unroll
    for (int ni = 0; ni < NI; ni++) {
        const int node = n0 + ni * 16 + lm;
        if (node >= M) continue;
#pragma unroll
        for (int mi = 0; mi < MI; mi++) {
            const int cb = c0 + mi * 16 + q * 4;
            float4 bv = BIAS ? *(const float4*)&bias[cb] : make_float4(0.f, 0.f, 0.f, 0.f);
            float v0 = fmaf(acc[ni][mi][0], 0.0625f, bv.x);
            float v1 = fmaf(acc[ni][mi][1], 0.0625f, bv.y);
            float v2 = fmaf(acc[ni][mi][2], 0.0625f, bv.z);
            float v3 = fmaf(acc[ni][mi][3], 0.0625f, bv.w);
            if constexpr (F32OUT) {
                *(float4*)((float*)Cout + (size_t)(orow0 + node) * NOUT + cb) =
                    make_float4(v0, v1, v2, v3);
            } else {
                __half2 h0 = __floats2half2_rn(v0, v1);
                __half2 h1 = __floats2half2_rn(v2, v3);
                uint2 o; o.x = *(unsigned*)&h0; o.y = *(unsigned*)&h1;
                *(uint2*)((__half*)Cout + (size_t)(orow0 + node) * NOUT + cb) = o;
            }
        }
    }
}

template <typename AT, int K, int KPAD, int NI, int MI, int NOUT, bool BIAS, bool F32OUT>
__launch_bounds__(256)
__global__ void k_gemm_reg(const AT* __restrict__ X,
                           const __half* __restrict__ Wh, const __half* __restrict__ Wl,
                           const float* __restrict__ bias, void* __restrict__ Cout,
                           int M, int orow0) {
    gemm_body<AT, K, KPAD, NI, MI, NOUT, BIAS, F32OUT>(X, Wh, Wl, bias, Cout, M, orow0, blockIdx.x);
}

// ---------------------------------------------------------------- fill + input transforms (one launch)
// blocks [0,782): user gemm; [782,2345): prod gemm; [2345,2345+2344): CSR fill
#define BLK_U 782
#define BLK_P 1563
#define BLK_F 2344
__launch_bounds__(256)
__global__ void k_fill_inputs(const int* __restrict__ src, const int* __restrict__ dst,
                              const int* __restrict__ offs, const int* __restrict__ bsums,
                              const int* __restrict__ rank, const float* __restrict__ dinv,
                              int2* __restrict__ epack,
                              const __half* __restrict__ xU, const __half* __restrict__ xP,
                              const __half* __restrict__ whU, const __half* __restrict__ wlU,
                              const __half* __restrict__ whP, const __half* __restrict__ wlP,
                              const float* __restrict__ bu, const float* __restrict__ bp,
                              void* __restrict__ xA) {
    const int b = blockIdx.x;
    if (b < BLK_U) {
        gemm_body<__half,  64,  64, 2, 4, 128, true, false>(xU, whU, wlU, bu, xA, NU, 0, b);
    } else if (b < BLK_U + BLK_P) {
        gemm_body<__half, 128, 128, 2, 2, 128, true, false>(xP, whP, wlP, bp, xA, NP, NU, b - BLK_U);
    } else {
        int e = (b - BLK_U - BLK_P) * 256 + threadIdx.x;
        if (e < NE) {
            int s = src[e], d = dst[e];
            int p = offs[d] + bsums[d >> 10] + rank[e];
            int2 r;
            r.x = s;
            r.y = __float_as_int(dinv[s] * dinv[d]);
            epack[p] = r;
        }
    }
}

// ---------------------------------------------------------------- CSR gather + bias + ReLU
// R6/R8-measured structure (40us, FETCH 93MB) + ONE fix: invalid tail slots
// previously gathered RANDOM neighbor-list rows with w=0 (~25% wasted fabric
// traffic at avg degree 6 / batch 8). Now clamped to the node's own row,
// which is L1-hot from the sv preload -> dead slots become near-free.
__launch_bounds__(256)
__global__ void k_aggregate(const __half* __restrict__ y, const int* __restrict__ offs,
                            const int* __restrict__ bsums, const int2* __restrict__ epack,
                            const float* __restrict__ dinv, const float* __restrict__ bias,
                            __half* __restrict__ out) {
    const int node = __builtin_amdgcn_readfirstlane(blockIdx.x * 4 + (threadIdx.x >> 6));
    const int l = threadIdx.x & 63;
    const int h = l >> 5, j = l & 31;

    int e0 = offs[node] + bsums[node >> 10];
    int e1 = (node + 1 < NN) ? (offs[node + 1] + bsums[(node + 1) >> 10]) : NE;
    e0 = __builtin_amdgcn_readfirstlane(e0);
    e1 = __builtin_amdgcn_readfirstlane(e1);

    const h4v* y4 = (const h4v*)y;               // row stride = 32 (8B units)

    const float di2 = dinv[node] * dinv[node];
    h4v sv = y4[(size_t)node * 32 + j];
    float4 bv = *(const float4*)&bias[4 * j];

    f32x4 acc0 = (f32x4)0.f, acc1 = (f32x4)0.f, acc2 = (f32x4)0.f, acc3 = (f32x4)0.f;

    for (int e = e0; e < e1; e += 8) {
        const int eb = e + 4 * h;
        const int2* pe = epack + eb;
        int2 p0 = pe[0];                          // contiguous 32B per half
        int2 p1 = pe[1];
        int2 p2 = pe[2];
        int2 p3 = pe[3];
        const bool k0 = (eb + 0 < e1), k1 = (eb + 1 < e1);
        const bool k2 = (eb + 2 < e1), k3 = (eb + 3 < e1);
        float w0 = k0 ? __int_as_float(p0.y) : 0.f;
        float w1 = k1 ? __int_as_float(p1.y) : 0.f;
        float w2 = k2 ? __int_as_float(p2.y) : 0.f;
        float w3 = k3 ? __int_as_float(p3.y) : 0.f;
        const int s0 = k0 ? p0.x : node;          // dead slot -> self row (L1-hot)
        const int s1 = k1 ? p1.x : node;
        const int s2 = k2 ? p2.x : node;
        const int s3 = k3 ? p3.x : node;
        h4v v0 = y4[(size_t)s0 * 32 + j];         // 2 full rows per gather instr
        h4v v1 = y4[(size_t)s1 * 32 + j];
        h4v v2 = y4[(size_t)s2 * 32 + j];
        h4v v3 = y4[(size_t)s3 * 32 + j];
        acc0[0] = fmaf((float)v0[0], w0, acc0[0]); acc0[1] = fmaf((float)v0[1], w0, acc0[1]);
        acc0[2] = fmaf((float)v0[2], w0, acc0[2]); acc0[3] = fmaf((float)v0[3], w0, acc0[3]);
        acc1[0] = fmaf((float)v1[0], w1, acc1[0]); acc1[1] = fmaf((float)v1[1], w1, acc1[1]);
        acc1[2] = fmaf((float)v1[2], w1, acc1[2]); acc1[3] = fmaf((float)v1[3], w1, acc1[3]);
        acc2[0] = fmaf((float)v2[0], w2, acc2[0]); acc2[1] = fmaf((float)v2[1], w2, acc2[1]);
        acc2[2] = fmaf((float)v2[2], w2, acc2[2]); acc2[3] = fmaf((float)v2[3], w2, acc2[3]);
        acc3[0] = fmaf((float)v3[0], w3, acc3[0]); acc3[1] = fmaf((float)v3[1], w3, acc3[1]);
        acc3[2] = fmaf((float)v3[2], w3, acc3[2]); acc3[3] = fmaf((float)v3[3], w3, acc3[3]);
    }

    f32x4 s = (acc0 + acc1) + (acc2 + acc3);
    float t0 = s[0] + __shfl_xor(s[0], 32, 64);
    float t1 = s[1] + __shfl_xor(s[1], 32, 64);
    float t2 = s[2] + __shfl_xor(s[2], 32, 64);
    float t3 = s[3] + __shfl_xor(s[3], 32, 64);

    float r0 = fmaf((float)sv[0], di2, t0) + bv.x;
    float r1 = fmaf((float)sv[1], di2, t1) + bv.y;
    float r2 = fmaf((float)sv[2], di2, t2) + bv.z;
    float r3 = fmaf((float)sv[3], di2, t3) + bv.w;
    if (l < 32) {
        __half2 ha = __floats2half2_rn(fmaxf(r0, 0.f), fmaxf(r1, 0.f));
        __half2 hb = __floats2half2_rn(fmaxf(r2, 0.f), fmaxf(r3, 0.f));
        uint2 o; o.x = *(unsigned*)&ha; o.y = *(unsigned*)&hb;
        *(uint2*)(out + (size_t)node * H + 4 * j) = o;
    }
}

// ---------------------------------------------------------------- launch
extern "C" void kernel_launch(void* const* d_in, const int* in_sizes, int n_in,
                              void* d_out, int out_size, void* d_ws, size_t ws_size,
                              hipStream_t stream) {
    const float* user = (const float*)d_in[0];
    const float* prod = (const float*)d_in[1];
    const int*   eidx = (const int*)  d_in[2];
    const int*   edst = eidx + NE;
    const int*   esrc = eidx;
    const float* Wu = (const float*)d_in[3];
    const float* bu = (const float*)d_in[4];
    const float* Wp = (const float*)d_in[5];
    const float* bp = (const float*)d_in[6];
    const float* W1 = (const float*)d_in[7];
    const float* b1 = (const float*)d_in[8];
    const float* W2 = (const float*)d_in[9];
    const float* b2 = (const float*)d_in[10];
    const float* W3 = (const float*)d_in[11];
    const float* b3 = (const float*)d_in[12];
    const float* Wo = (const float*)d_in[13];
    const float* bo = (const float*)d_in[14];
    float* out = (float*)d_out;

    char* ws = (char*)d_ws;
    size_t p = 0;
    auto alloc = [&](size_t bytes) -> void* {
        void* r = ws + p;
        p += (bytes + 255) & ~(size_t)255;
        return r;
    };
    __half* xA   = (__half*)alloc((size_t)NN * H * 2);
    __half* xB   = (__half*)alloc((size_t)NN * H * 2);
    __half* xU   = (__half*)alloc((size_t)NU * 64 * 2);
    __half* xP   = (__half*)alloc((size_t)NP * 128 * 2);
    int*   cnt   = (int*)  alloc((size_t)NN * 4);
    int*   rank  = (int*)  alloc((size_t)NE * 4);
    int*   offs  = (int*)  alloc((size_t)(NN + 1) * 4);
    float* dinv  = (float*)alloc((size_t)NN * 4);
    int2*  epack = (int2*) alloc((size_t)(NE + 8) * 8);
    int*   bsums = (int*)  alloc(128 * 4);
    __half* whU = (__half*)alloc(128 * 64 * 2);
    __half* wlU = (__half*)alloc(128 * 64 * 2);
    __half* whP = (__half*)alloc(128 * 128 * 2);
    __half* wlP = (__half*)alloc(128 * 128 * 2);
    __half* wh1 = (__half*)alloc(128 * 128 * 2);
    __half* wl1 = (__half*)alloc(128 * 128 * 2);
    __half* wh2 = (__half*)alloc(128 * 128 * 2);
    __half* wl2 = (__half*)alloc(128 * 128 * 2);
    __half* wh3 = (__half*)alloc(128 * 128 * 2);
    __half* wl3 = (__half*)alloc(128 * 128 * 2);
    __half* whO = (__half*)alloc(16 * 128 * 2);
    __half* wlO = (__half*)alloc(16 * 128 * 2);

    const int NBLK = (NN + SCAN_CHUNK - 1) / SCAN_CHUNK;   // 98

    // prep (weights + cnt + epack pad + fp16 input conversion)
    {
        const int total = 175784 + NU * 16 + NP * 32;
        k_prep<<<(total + 255) / 256, 256, 0, stream>>>(
            Wu, Wp, W1, W2, W3, Wo, user, prod,
            whU, wlU, whP, wlP, wh1, wl1, wh2, wl2, wh3, wl3, whO, wlO,
            xU, xP, cnt, epack);
    }

    // graph structure
    k_count<<<(NE + 255) / 256, 256, 0, stream>>>(edst, cnt, rank, NE);
    k_scan1<<<NBLK, SCAN_TPB, 0, stream>>>(cnt, offs, bsums, dinv, NN);
    k_scan2<<<1, 128, 0, stream>>>(bsums, NBLK);

    // CSR fill + user/prod input transforms (one launch, block-range split)
    k_fill_inputs<<<BLK_U + BLK_P + BLK_F, 256, 0, stream>>>(
        esrc, edst, offs, bsums, rank, dinv, epack,
        xU, xP, whU, wlU, whP, wlP, bu, bp, xA);

    // hidden gemms: NT=1563, CSPLIT=2 -> 3126 waves -> 782 blocks
    const int blkG = (1563 * 2 + 3) / 4;   // 782
    const int blkO = (1563 + 3) / 4;       // 391

    // layer 1
    k_gemm_reg<__half, 128, 128, 4, 4, 128, false, false><<<blkG, 256, 0, stream>>>(xA, wh1, wl1, nullptr, xB, NN, 0);
    k_aggregate<<<NN / 4, 256, 0, stream>>>(xB, offs, bsums, epack, dinv, b1, xA);
    // layer 2
    k_gemm_reg<__half, 128, 128, 4, 4, 128, false, false><<<blkG, 256, 0, stream>>>(xA, wh2, wl2, nullptr, xB, NN, 0);
    k_aggregate<<<NN / 4, 256, 0, stream>>>(xB, offs, bsums, epack, dinv, b2, xA);
    // layer 3
    k_gemm_reg<__half, 128, 128, 4, 4, 128, false, false><<<blkG, 256, 0, stream>>>(xA, wh3, wl3, nullptr, xB, NN, 0);
    k_aggregate<<<NN / 4, 256, 0, stream>>>(xB, offs, bsums, epack, dinv, b3, xA);

    // output head [NN,128] @ [128,16] + bo -> fp32 out
    k_gemm_reg<__half, 128, 128, 4, 1, 16, true, true><<<blkO, 256, 0, stream>>>(xA, whO, wlO, bo, out, NN, 0);
}

// Round 11
// 263.960 us; speedup vs baseline: 1.1616x; 1.1045x over previous
//
#include <hip/hip_runtime.h>
#include <hip/hip_fp16.h>

#define NU 50000
#define NP 50000
#define NN 100000
#define NE 600000
#define H  128
#define O  16

typedef __attribute__((ext_vector_type(8))) _Float16 half8;
typedef __attribute__((ext_vector_type(4))) _Float16 h4v;
typedef __attribute__((ext_vector_type(4))) float f32x4;

// ---------------------------------------------------------------- fused prep
// Layer-1 is COMPOSED into the input weights (no relu between input transform
// and x@W1, both linear):  Wu1 = Wu@W1 (fp32-exact), bu1 = bu@W1, same for prod.
// Ranges:
// [0,8192)            : Wu1 composed decomposition (KPAD=64)
// [8192,24576)        : Wp1 composed (KPAD=128, k>=100 -> 0)
// [24576,40960)       : W2 decomposition
// [40960,57344)       : W3 decomposition
// [57344,59392)       : Wo decomposition (NC=16)
// [59392,59648)       : bu1 / bp1 composed fp32 biases
// [59648,+NN)         : zero cnt
// [+NN,+8)            : zero epack pad
// [159656,+NU*16)     : user fp32 -> fp16   (xU [NU][64])
// [+NU*16,+NP*32)     : prod fp32 -> fp16 pad (xP [NP][128])
__global__ void k_prep(const float* __restrict__ Wu, const float* __restrict__ Wp,
                       const float* __restrict__ W1, const float* __restrict__ W2,
                       const float* __restrict__ W3, const float* __restrict__ Wo,
                       const float* __restrict__ user, const float* __restrict__ prod,
                       const float* __restrict__ bu, const float* __restrict__ bp,
                       __half* __restrict__ whU1, __half* __restrict__ wlU1,
                       __half* __restrict__ whP1, __half* __restrict__ wlP1,
                       __half* __restrict__ wh2, __half* __restrict__ wl2,
                       __half* __restrict__ wh3, __half* __restrict__ wl3,
                       __half* __restrict__ whO, __half* __restrict__ wlO,
                       float* __restrict__ bu1, float* __restrict__ bp1,
                       __half* __restrict__ xU, __half* __restrict__ xP,
                       int* __restrict__ cnt, int2* __restrict__ epack) {
    int idx = blockIdx.x * blockDim.x + threadIdx.x;
    if (idx >= 159656) {                       // feature conversions
        int i = idx - 159656;
        if (i < NU * 16) {
            int e = i * 4;
            float4 v = *(const float4*)(user + e);
            __half2 a = __floats2half2_rn(v.x, v.y);
            __half2 b = __floats2half2_rn(v.z, v.w);
            uint2 o; o.x = *(unsigned*)&a; o.y = *(unsigned*)&b;
            *(uint2*)(xU + e) = o;
        } else {
            int q = i - NU * 16;
            if (q >= NP * 32) return;
            int row = q >> 5, kq = (q & 31) * 4;
            float4 v;
            if (kq < 100) v = *(const float4*)(prod + row * 100 + kq);
            else { v.x = 0.f; v.y = 0.f; v.z = 0.f; v.w = 0.f; }
            __half2 a = __floats2half2_rn(v.x, v.y);
            __half2 b = __floats2half2_rn(v.z, v.w);
            uint2 o; o.x = *(unsigned*)&a; o.y = *(unsigned*)&b;
            *(uint2*)(xP + (size_t)row * 128 + kq) = o;
        }
        return;
    }
    if (idx >= 59648) {                        // cnt zero + epack pad
        int i = idx - 59648;
        if (i < NN) cnt[i] = 0;
        else if (i < NN + 8) { int2 z; z.x = 0; z.y = 0; epack[NE + (i - NN)] = z; }
        return;
    }
    if (idx >= 59392) {                        // composed biases (fp32)
        int n = idx - 59392;
        const float* bsrc = (n < 128) ? bu : bp;
        int nn = n & 127;
        float acc = 0.f;
        for (int j = 0; j < 128; ++j) acc = fmaf(bsrc[j], W1[j * 128 + nn], acc);
        if (n < 128) bu1[nn] = acc; else bp1[nn] = acc;
        return;
    }
    // weight decompositions
    float x;
    __half *Wh, *Wl; int sidx;
    if (idx < 8192) {                          // Wu1 = Wu@W1, [64][128] KPAD=64
        int n = idx >> 6, k = idx & 63;
        float acc = 0.f;
        for (int j = 0; j < 128; ++j) acc = fmaf(Wu[k * 128 + j], W1[j * 128 + n], acc);
        x = acc * 16.0f; Wh = whU1; Wl = wlU1; sidx = idx;
    } else if (idx < 24576) {                  // Wp1 = Wp@W1, [100->128][128]
        int l = idx - 8192;
        int n = l >> 7, k = l & 127;
        float acc = 0.f;
        if (k < 100)
            for (int j = 0; j < 128; ++j) acc = fmaf(Wp[k * 128 + j], W1[j * 128 + n], acc);
        x = acc * 16.0f; Wh = whP1; Wl = wlP1; sidx = l;
    } else if (idx < 40960) {                  // W2
        int l = idx - 24576;
        int n = l >> 7, k = l & 127;
        x = W2[k * 128 + n] * 16.0f; Wh = wh2; Wl = wl2; sidx = l;
    } else if (idx < 57344) {                  // W3
        int l = idx - 40960;
        int n = l >> 7, k = l & 127;
        x = W3[k * 128 + n] * 16.0f; Wh = wh3; Wl = wl3; sidx = l;
    } else {                                   // Wo [128][16]
        int l = idx - 57344;
        int n = l >> 7, k = l & 127;
        x = Wo[k * 16 + n] * 16.0f; Wh = whO; Wl = wlO; sidx = l;
    }
    __half h = __float2half_rn(x);
    __half l2 = __float2half_rn(x - __half2float(h));
    Wh[sidx] = h; Wl[sidx] = l2;
}

// ---------------------------------------------------------------- degree count + rank
__global__ void k_count(const int* __restrict__ dst, int* __restrict__ cnt,
                        int* __restrict__ rank, int E) {
    int e = blockIdx.x * blockDim.x + threadIdx.x;
    if (e < E) rank[e] = atomicAdd(&cnt[dst[e]], 1);
}

// ---------------------------------------------------------------- exclusive scan
#define SCAN_TPB 256
#define SCAN_VPT 4
#define SCAN_CHUNK (SCAN_TPB * SCAN_VPT)   // 1024 -> consumers use >>10

__global__ void k_scan1(const int* __restrict__ in, int* __restrict__ out,
                        int* __restrict__ bsums, float* __restrict__ dinv, int n) {
    __shared__ int sh[SCAN_TPB];
    int t = threadIdx.x, b = blockIdx.x;
    int base = b * SCAN_CHUNK + t * SCAN_VPT;
    int v[SCAN_VPT]; int s = 0;
#pragma unroll
    for (int i = 0; i < SCAN_VPT; i++) {
        int idx = base + i;
        v[i] = (idx < n) ? in[idx] : 0;
        if (idx < n) dinv[idx] = rsqrtf((float)(v[i] + 1));
        s += v[i];
    }
    sh[t] = s; __syncthreads();
    for (int off = 1; off < SCAN_TPB; off <<= 1) {
        int x = (t >= off) ? sh[t - off] : 0;
        __syncthreads();
        sh[t] += x;
        __syncthreads();
    }
    int run = (t > 0) ? sh[t - 1] : 0;
    if (t == SCAN_TPB - 1) bsums[b] = sh[t];
#pragma unroll
    for (int i = 0; i < SCAN_VPT; i++) {
        int idx = base + i;
        if (idx < n) out[idx] = run;
        run += v[i];
    }
}

__global__ void k_scan2(int* __restrict__ bsums, int nb) {
    __shared__ int sh[128];
    int t = threadIdx.x;
    int v = (t < nb) ? bsums[t] : 0;
    sh[t] = v; __syncthreads();
    for (int off = 1; off < 128; off <<= 1) {
        int x = (t >= off) ? sh[t - off] : 0;
        __syncthreads();
        sh[t] += x;
        __syncthreads();
    }
    if (t < nb) bsums[t] = sh[t] - v;
}

// ---------------------------------------------------------------- register-resident MFMA GEMM
template <typename AT, int K, int KPAD, int NI, int MI, int NOUT, bool BIAS, bool F32OUT>
__device__ __forceinline__
void gemm_body(const AT* __restrict__ X,
               const __half* __restrict__ Wh, const __half* __restrict__ Wl,
               const float* __restrict__ bias, void* __restrict__ Cout,
               int M, int orow0, int vb) {
    constexpr int KS = KPAD / 32;
    constexpr int CSPLIT = NOUT / (16 * MI);
    const int tid  = threadIdx.x;
    const int wid  = tid >> 6, lane = tid & 63;
    const int lm   = lane & 15, q = lane >> 4;
    const int gw   = vb * 4 + wid;
    const int tile = gw / CSPLIT;
    const int c0   = (gw % CSPLIT) * (MI * 16);
    const int NT   = (M + NI * 16 - 1) / (NI * 16);
    if (tile >= NT) return;
    const int n0 = tile * (NI * 16);

    half8 wh[MI][KS], wl[MI][KS];
#pragma unroll
    for (int mi = 0; mi < MI; mi++)
#pragma unroll
        for (int ks = 0; ks < KS; ks++) {
            const size_t b = (size_t)(c0 + mi * 16 + lm) * KPAD + ks * 32 + q * 8;
            wh[mi][ks] = *(const half8*)&Wh[b];
            wl[mi][ks] = *(const half8*)&Wl[b];
        }

    f32x4 acc[NI][MI];
#pragma unroll
    for (int ni = 0; ni < NI; ni++)
#pragma unroll
        for (int mi = 0; mi < MI; mi++) acc[ni][mi] = (f32x4)0.0f;

#pragma unroll
    for (int ni = 0; ni < NI; ni++) {
        const int node = n0 + ni * 16 + lm;
        half8 xf[KS];
        if (node < M) {
#pragma unroll
            for (int ks = 0; ks < KS; ks++)
                xf[ks] = *(const half8*)((const __half*)X + (size_t)node * KPAD + ks * 32 + q * 8);
        } else {
#pragma unroll
            for (int ks = 0; ks < KS; ks++)
#pragma unroll
                for (int j = 0; j < 8; j++) xf[ks][j] = (_Float16)0.0f;
        }
#pragma unroll
        for (int ks = 0; ks < KS; ks++)
#pragma unroll
            for (int mi = 0; mi < MI; mi++) {
                acc[ni][mi] = __builtin_amdgcn_mfma_f32_16x16x32_f16(wh[mi][ks], xf[ks], acc[ni][mi], 0, 0, 0);
                acc[ni][mi] = __builtin_amdgcn_mfma_f32_16x16x32_f16(wl[mi][ks], xf[ks], acc[ni][mi], 0, 0, 0);
            }
    }

#pragma unroll
    for (int ni = 0; ni < NI; ni++) {
        const int node = n0 + ni * 16 + lm;
        if (node >= M) continue;
#pragma unroll
        for (int mi = 0; mi < MI; mi++) {
            const int cb = c0 + mi * 16 + q * 4;
            float4 bv = BIAS ? *(const float4*)&bias[cb] : make_float4(0.f, 0.f, 0.f, 0.f);
            float v0 = fmaf(acc[ni][mi][0], 0.0625f, bv.x);
            float v1 = fmaf(acc[ni][mi][1], 0.0625f, bv.y);
            float v2 = fmaf(acc[ni][mi][2], 0.0625f, bv.z);
            float v3 = fmaf(acc[ni][mi][3], 0.0625f, bv.w);
            if constexpr (F32OUT) {
                *(float4*)((float*)Cout + (size_t)(orow0 + node) * NOUT + cb) =
                    make_float4(v0, v1, v2, v3);
            } else {
                __half2 h0 = __floats2half2_rn(v0, v1);
                __half2 h1 = __floats2half2_rn(v2, v3);
                uint2 o; o.x = *(unsigned*)&h0; o.y = *(unsigned*)&h1;
                *(uint2*)((__half*)Cout + (size_t)(orow0 + node) * NOUT + cb) = o;
            }
        }
    }
}

template <typename AT, int K, int KPAD, int NI, int MI, int NOUT, bool BIAS, bool F32OUT>
__launch_bounds__(256)
__global__ void k_gemm_reg(const AT* __restrict__ X,
                           const __half* __restrict__ Wh, const __half* __restrict__ Wl,
                           const float* __restrict__ bias, void* __restrict__ Cout,
                           int M, int orow0) {
    gemm_body<AT, K, KPAD, NI, MI, NOUT, BIAS, F32OUT>(X, Wh, Wl, bias, Cout, M, orow0, blockIdx.x);
}

// ---------------------------------------------------------------- fill + LAYER-1 gemm (composed)
// g1 = x0@W1 computed DIRECTLY from raw fp16 inputs via composed weights:
// user rows: xU @ Wu1 + bu1 ; prod rows: xP @ Wp1 + bp1  -> xB.
// The former separate input-transform gemm + 51.2MB xA round-trip are gone.
// blocks [0,782): user g1; [782,2345): prod g1; [2345,+2344): CSR fill
#define BLK_U 782
#define BLK_P 1563
#define BLK_F 2344
__launch_bounds__(256)
__global__ void k_fill_g1(const int* __restrict__ src, const int* __restrict__ dst,
                          const int* __restrict__ offs, const int* __restrict__ bsums,
                          const int* __restrict__ rank, const float* __restrict__ dinv,
                          int2* __restrict__ epack,
                          const __half* __restrict__ xU, const __half* __restrict__ xP,
                          const __half* __restrict__ whU1, const __half* __restrict__ wlU1,
                          const __half* __restrict__ whP1, const __half* __restrict__ wlP1,
                          const float* __restrict__ bu1, const float* __restrict__ bp1,
                          void* __restrict__ xB) {
    const int b = blockIdx.x;
    if (b < BLK_U) {
        gemm_body<__half,  64,  64, 2, 4, 128, true, false>(xU, whU1, wlU1, bu1, xB, NU, 0, b);
    } else if (b < BLK_U + BLK_P) {
        gemm_body<__half, 128, 128, 2, 2, 128, true, false>(xP, whP1, wlP1, bp1, xB, NP, NU, b - BLK_U);
    } else {
        int e = (b - BLK_U - BLK_P) * 256 + threadIdx.x;
        if (e < NE) {
            int s = src[e], d = dst[e];
            int p = offs[d] + bsums[d >> 10] + rank[e];
            int2 r;
            r.x = s;
            r.y = __float_as_int(dinv[s] * dinv[d]);
            epack[p] = r;
        }
    }
}

// ---------------------------------------------------------------- CSR gather + bias + ReLU
// (R10-measured: full 256B rows, 8B lanes, 2 rows/gather-instr, dead tail
// slots clamped to the L1-hot self row.)
__launch_bounds__(256)
__global__ void k_aggregate(const __half* __restrict__ y, const int* __restrict__ offs,
                            const int* __restrict__ bsums, const int2* __restrict__ epack,
                            const float* __restrict__ dinv, const float* __restrict__ bias,
                            __half* __restrict__ out) {
    const int node = __builtin_amdgcn_readfirstlane(blockIdx.x * 4 + (threadIdx.x >> 6));
    const int l = threadIdx.x & 63;
    const int h = l >> 5, j = l & 31;

    int e0 = offs[node] + bsums[node >> 10];
    int e1 = (node + 1 < NN) ? (offs[node + 1] + bsums[(node + 1) >> 10]) : NE;
    e0 = __builtin_amdgcn_readfirstlane(e0);
    e1 = __builtin_amdgcn_readfirstlane(e1);

    const h4v* y4 = (const h4v*)y;               // row stride = 32 (8B units)

    const float di2 = dinv[node] * dinv[node];
    h4v sv = y4[(size_t)node * 32 + j];
    float4 bv = *(const float4*)&bias[4 * j];

    f32x4 acc0 = (f32x4)0.f, acc1 = (f32x4)0.f, acc2 = (f32x4)0.f, acc3 = (f32x4)0.f;

    for (int e = e0; e < e1; e += 8) {
        const int eb = e + 4 * h;
        const int2* pe = epack + eb;
        int2 p0 = pe[0];                          // contiguous 32B per half
        int2 p1 = pe[1];
        int2 p2 = pe[2];
        int2 p3 = pe[3];
        const bool k0 = (eb + 0 < e1), k1 = (eb + 1 < e1);
        const bool k2 = (eb + 2 < e1), k3 = (eb + 3 < e1);
        float w0 = k0 ? __int_as_float(p0.y) : 0.f;
        float w1 = k1 ? __int_as_float(p1.y) : 0.f;
        float w2 = k2 ? __int_as_float(p2.y) : 0.f;
        float w3 = k3 ? __int_as_float(p3.y) : 0.f;
        const int s0 = k0 ? p0.x : node;          // dead slot -> self row (L1-hot)
        const int s1 = k1 ? p1.x : node;
        const int s2 = k2 ? p2.x : node;
        const int s3 = k3 ? p3.x : node;
        h4v v0 = y4[(size_t)s0 * 32 + j];         // 2 full rows per gather instr
        h4v v1 = y4[(size_t)s1 * 32 + j];
        h4v v2 = y4[(size_t)s2 * 32 + j];
        h4v v3 = y4[(size_t)s3 * 32 + j];
        acc0[0] = fmaf((float)v0[0], w0, acc0[0]); acc0[1] = fmaf((float)v0[1], w0, acc0[1]);
        acc0[2] = fmaf((float)v0[2], w0, acc0[2]); acc0[3] = fmaf((float)v0[3], w0, acc0[3]);
        acc1[0] = fmaf((float)v1[0], w1, acc1[0]); acc1[1] = fmaf((float)v1[1], w1, acc1[1]);
        acc1[2] = fmaf((float)v1[2], w1, acc1[2]); acc1[3] = fmaf((float)v1[3], w1, acc1[3]);
        acc2[0] = fmaf((float)v2[0], w2, acc2[0]); acc2[1] = fmaf((float)v2[1], w2, acc2[1]);
        acc2[2] = fmaf((float)v2[2], w2, acc2[2]); acc2[3] = fmaf((float)v2[3], w2, acc2[3]);
        acc3[0] = fmaf((float)v3[0], w3, acc3[0]); acc3[1] = fmaf((float)v3[1], w3, acc3[1]);
        acc3[2] = fmaf((float)v3[2], w3, acc3[2]); acc3[3] = fmaf((float)v3[3], w3, acc3[3]);
    }

    f32x4 s = (acc0 + acc1) + (acc2 + acc3);
    float t0 = s[0] + __shfl_xor(s[0], 32, 64);
    float t1 = s[1] + __shfl_xor(s[1], 32, 64);
    float t2 = s[2] + __shfl_xor(s[2], 32, 64);
    float t3 = s[3] + __shfl_xor(s[3], 32, 64);

    float r0 = fmaf((float)sv[0], di2, t0) + bv.x;
    float r1 = fmaf((float)sv[1], di2, t1) + bv.y;
    float r2 = fmaf((float)sv[2], di2, t2) + bv.z;
    float r3 = fmaf((float)sv[3], di2, t3) + bv.w;
    if (l < 32) {
        __half2 ha = __floats2half2_rn(fmaxf(r0, 0.f), fmaxf(r1, 0.f));
        __half2 hb = __floats2half2_rn(fmaxf(r2, 0.f), fmaxf(r3, 0.f));
        uint2 o; o.x = *(unsigned*)&ha; o.y = *(unsigned*)&hb;
        *(uint2*)(out + (size_t)node * H + 4 * j) = o;
    }
}

// ---------------------------------------------------------------- launch
extern "C" void kernel_launch(void* const* d_in, const int* in_sizes, int n_in,
                              void* d_out, int out_size, void* d_ws, size_t ws_size,
                              hipStream_t stream) {
    const float* user = (const float*)d_in[0];
    const float* prod = (const float*)d_in[1];
    const int*   eidx = (const int*)  d_in[2];
    const int*   edst = eidx + NE;
    const int*   esrc = eidx;
    const float* Wu = (const float*)d_in[3];
    const float* bu = (const float*)d_in[4];
    const float* Wp = (const float*)d_in[5];
    const float* bp = (const float*)d_in[6];
    const float* W1 = (const float*)d_in[7];
    const float* b1 = (const float*)d_in[8];
    const float* W2 = (const float*)d_in[9];
    const float* b2 = (const float*)d_in[10];
    const float* W3 = (const float*)d_in[11];
    const float* b3 = (const float*)d_in[12];
    const float* Wo = (const float*)d_in[13];
    const float* bo = (const float*)d_in[14];
    float* out = (float*)d_out;

    char* ws = (char*)d_ws;
    size_t p = 0;
    auto alloc = [&](size_t bytes) -> void* {
        void* r = ws + p;
        p += (bytes + 255) & ~(size_t)255;
        return r;
    };
    __half* xA   = (__half*)alloc((size_t)NN * H * 2);
    __half* xB   = (__half*)alloc((size_t)NN * H * 2);
    __half* xU   = (__half*)alloc((size_t)NU * 64 * 2);
    __half* xP   = (__half*)alloc((size_t)NP * 128 * 2);
    int*   cnt   = (int*)  alloc((size_t)NN * 4);
    int*   rank  = (int*)  alloc((size_t)NE * 4);
    int*   offs  = (int*)  alloc((size_t)(NN + 1) * 4);
    float* dinv  = (float*)alloc((size_t)NN * 4);
    int2*  epack = (int2*) alloc((size_t)(NE + 8) * 8);
    int*   bsums = (int*)  alloc(128 * 4);
    __half* whU1 = (__half*)alloc(128 * 64 * 2);
    __half* wlU1 = (__half*)alloc(128 * 64 * 2);
    __half* whP1 = (__half*)alloc(128 * 128 * 2);
    __half* wlP1 = (__half*)alloc(128 * 128 * 2);
    __half* wh2 = (__half*)alloc(128 * 128 * 2);
    __half* wl2 = (__half*)alloc(128 * 128 * 2);
    __half* wh3 = (__half*)alloc(128 * 128 * 2);
    __half* wl3 = (__half*)alloc(128 * 128 * 2);
    __half* whO = (__half*)alloc(16 * 128 * 2);
    __half* wlO = (__half*)alloc(16 * 128 * 2);
    float* bu1  = (float*)alloc(128 * 4);
    float* bp1  = (float*)alloc(128 * 4);

    const int NBLK = (NN + SCAN_CHUNK - 1) / SCAN_CHUNK;   // 98

    // prep: composed weights + decompositions + cnt + epack pad + fp16 inputs
    {
        const int total = 159656 + NU * 16 + NP * 32;      // 2,559,656
        k_prep<<<(total + 255) / 256, 256, 0, stream>>>(
            Wu, Wp, W1, W2, W3, Wo, user, prod, bu, bp,
            whU1, wlU1, whP1, wlP1, wh2, wl2, wh3, wl3, whO, wlO,
            bu1, bp1, xU, xP, cnt, epack);
    }

    // graph structure
    k_count<<<(NE + 255) / 256, 256, 0, stream>>>(edst, cnt, rank, NE);
    k_scan1<<<NBLK, SCAN_TPB, 0, stream>>>(cnt, offs, bsums, dinv, NN);
    k_scan2<<<1, 128, 0, stream>>>(bsums, NBLK);

    // CSR fill + layer-1 gemm (composed weights) -> xB, one launch
    k_fill_g1<<<BLK_U + BLK_P + BLK_F, 256, 0, stream>>>(
        esrc, edst, offs, bsums, rank, dinv, epack,
        xU, xP, whU1, wlU1, whP1, wlP1, bu1, bp1, xB);

    const int blkG = (1563 * 2 + 3) / 4;   // 782
    const int blkO = (1563 + 3) / 4;       // 391

    // layer 1 aggregate
    k_aggregate<<<NN / 4, 256, 0, stream>>>(xB, offs, bsums, epack, dinv, b1, xA);
    // layer 2
    k_gemm_reg<__half, 128, 128, 4, 4, 128, false, false><<<blkG, 256, 0, stream>>>(xA, wh2, wl2, nullptr, xB, NN, 0);
    k_aggregate<<<NN / 4, 256, 0, stream>>>(xB, offs, bsums, epack, dinv, b2, xA);
    // layer 3
    k_gemm_reg<__half, 128, 128, 4, 4, 128, false, false><<<blkG, 256, 0, stream>>>(xA, wh3, wl3, nullptr, xB, NN, 0);
    k_aggregate<<<NN / 4, 256, 0, stream>>>(xB, offs, bsums, epack, dinv, b3, xA);

    // output head [NN,128] @ [128,16] + bo -> fp32 out
    k_gemm_reg<__half, 128, 128, 4, 1, 16, true, true><<<blkO, 256, 0, stream>>>(xA, whO, wlO, bo, out, NN, 0);
}

// Round 12
// 257.460 us; speedup vs baseline: 1.1910x; 1.0252x over previous
//
#include <hip/hip_runtime.h>
#include <hip/hip_fp16.h>

#define NU 50000
#define NP 50000
#define NN 100000
#define NE 600000
#define H  128
#define O  16

typedef __attribute__((ext_vector_type(8))) _Float16 half8;
typedef __attribute__((ext_vector_type(4))) _Float16 h4v;
typedef __attribute__((ext_vector_type(4))) float f32x4;

// ---------------------------------------------------------------- fused prep
// Layer-1 composed into input weights: Wu1 = Wu@W1, bu1 = bu@W1 (fp32-exact).
// cnt is zeroed by hipMemsetAsync BEFORE this kernel; degree-count atomics are
// folded in here as the tail range (overlap with the streaming conversions).
// Ranges:
// [0,8192)             : Wu1 composed decomposition (KPAD=64)
// [8192,24576)         : Wp1 composed (KPAD=128, k>=100 -> 0)
// [24576,40960)        : W2 decomposition
// [40960,57344)        : W3 decomposition
// [57344,59392)        : Wo decomposition (NC=16)
// [59392,59648)        : bu1 / bp1 composed fp32 biases
// [59648,59656)        : zero epack pad (8 entries)
// [59656,859656)       : user fp32 -> fp16   (xU [NU][64])
// [859656,2459656)     : prod fp32 -> fp16 pad (xP [NP][128])
// [2459656,3059656)    : degree count + rank (atomicAdd)
__global__ void k_prep(const float* __restrict__ Wu, const float* __restrict__ Wp,
                       const float* __restrict__ W1, const float* __restrict__ W2,
                       const float* __restrict__ W3, const float* __restrict__ Wo,
                       const float* __restrict__ user, const float* __restrict__ prod,
                       const float* __restrict__ bu, const float* __restrict__ bp,
                       const int* __restrict__ edst,
                       __half* __restrict__ whU1, __half* __restrict__ wlU1,
                       __half* __restrict__ whP1, __half* __restrict__ wlP1,
                       __half* __restrict__ wh2, __half* __restrict__ wl2,
                       __half* __restrict__ wh3, __half* __restrict__ wl3,
                       __half* __restrict__ whO, __half* __restrict__ wlO,
                       float* __restrict__ bu1, float* __restrict__ bp1,
                       __half* __restrict__ xU, __half* __restrict__ xP,
                       int* __restrict__ cnt, int* __restrict__ rank,
                       int2* __restrict__ epack) {
    int idx = blockIdx.x * blockDim.x + threadIdx.x;
    if (idx >= 2459656) {                      // degree count + rank
        int e = idx - 2459656;
        if (e < NE) rank[e] = atomicAdd(&cnt[edst[e]], 1);
        return;
    }
    if (idx >= 859656) {                       // prod conversion
        int q = idx - 859656;
        int row = q >> 5, kq = (q & 31) * 4;
        float4 v;
        if (kq < 100) v = *(const float4*)(prod + row * 100 + kq);
        else { v.x = 0.f; v.y = 0.f; v.z = 0.f; v.w = 0.f; }
        __half2 a = __floats2half2_rn(v.x, v.y);
        __half2 b = __floats2half2_rn(v.z, v.w);
        uint2 o; o.x = *(unsigned*)&a; o.y = *(unsigned*)&b;
        *(uint2*)(xP + (size_t)row * 128 + kq) = o;
        return;
    }
    if (idx >= 59656) {                        // user conversion
        int e = (idx - 59656) * 4;
        float4 v = *(const float4*)(user + e);
        __half2 a = __floats2half2_rn(v.x, v.y);
        __half2 b = __floats2half2_rn(v.z, v.w);
        uint2 o; o.x = *(unsigned*)&a; o.y = *(unsigned*)&b;
        *(uint2*)(xU + e) = o;
        return;
    }
    if (idx >= 59648) {                        // epack pad
        int2 z; z.x = 0; z.y = 0;
        epack[NE + (idx - 59648)] = z;
        return;
    }
    if (idx >= 59392) {                        // composed biases (fp32)
        int n = idx - 59392;
        const float* bsrc = (n < 128) ? bu : bp;
        int nn = n & 127;
        float acc = 0.f;
        for (int j = 0; j < 128; ++j) acc = fmaf(bsrc[j], W1[j * 128 + nn], acc);
        if (n < 128) bu1[nn] = acc; else bp1[nn] = acc;
        return;
    }
    // weight decompositions
    float x;
    __half *Wh, *Wl; int sidx;
    if (idx < 8192) {                          // Wu1 = Wu@W1, [64][128] KPAD=64
        int n = idx >> 6, k = idx & 63;
        float acc = 0.f;
        for (int j = 0; j < 128; ++j) acc = fmaf(Wu[k * 128 + j], W1[j * 128 + n], acc);
        x = acc * 16.0f; Wh = whU1; Wl = wlU1; sidx = idx;
    } else if (idx < 24576) {                  // Wp1 = Wp@W1, [100->128][128]
        int l = idx - 8192;
        int n = l >> 7, k = l & 127;
        float acc = 0.f;
        if (k < 100)
            for (int j = 0; j < 128; ++j) acc = fmaf(Wp[k * 128 + j], W1[j * 128 + n], acc);
        x = acc * 16.0f; Wh = whP1; Wl = wlP1; sidx = l;
    } else if (idx < 40960) {                  // W2
        int l = idx - 24576;
        int n = l >> 7, k = l & 127;
        x = W2[k * 128 + n] * 16.0f; Wh = wh2; Wl = wl2; sidx = l;
    } else if (idx < 57344) {                  // W3
        int l = idx - 40960;
        int n = l >> 7, k = l & 127;
        x = W3[k * 128 + n] * 16.0f; Wh = wh3; Wl = wl3; sidx = l;
    } else {                                   // Wo [128][16]
        int l = idx - 57344;
        int n = l >> 7, k = l & 127;
        x = Wo[k * 16 + n] * 16.0f; Wh = whO; Wl = wlO; sidx = l;
    }
    __half h = __float2half_rn(x);
    __half l2 = __float2half_rn(x - __half2float(h));
    Wh[sidx] = h; Wl[sidx] = l2;
}

// ---------------------------------------------------------------- exclusive scan
#define SCAN_TPB 256
#define SCAN_VPT 4
#define SCAN_CHUNK (SCAN_TPB * SCAN_VPT)   // 1024 -> consumers use >>10

__global__ void k_scan1(const int* __restrict__ in, int* __restrict__ out,
                        int* __restrict__ bsums, float* __restrict__ dinv, int n) {
    __shared__ int sh[SCAN_TPB];
    int t = threadIdx.x, b = blockIdx.x;
    int base = b * SCAN_CHUNK + t * SCAN_VPT;
    int v[SCAN_VPT]; int s = 0;
#pragma unroll
    for (int i = 0; i < SCAN_VPT; i++) {
        int idx = base + i;
        v[i] = (idx < n) ? in[idx] : 0;
        if (idx < n) dinv[idx] = rsqrtf((float)(v[i] + 1));
        s += v[i];
    }
    sh[t] = s; __syncthreads();
    for (int off = 1; off < SCAN_TPB; off <<= 1) {
        int x = (t >= off) ? sh[t - off] : 0;
        __syncthreads();
        sh[t] += x;
        __syncthreads();
    }
    int run = (t > 0) ? sh[t - 1] : 0;
    if (t == SCAN_TPB - 1) bsums[b] = sh[t];
#pragma unroll
    for (int i = 0; i < SCAN_VPT; i++) {
        int idx = base + i;
        if (idx < n) out[idx] = run;
        run += v[i];
    }
}

__global__ void k_scan2(int* __restrict__ bsums, int nb) {
    __shared__ int sh[128];
    int t = threadIdx.x;
    int v = (t < nb) ? bsums[t] : 0;
    sh[t] = v; __syncthreads();
    for (int off = 1; off < 128; off <<= 1) {
        int x = (t >= off) ? sh[t - off] : 0;
        __syncthreads();
        sh[t] += x;
        __syncthreads();
    }
    if (t < nb) bsums[t] = sh[t] - v;
}

// ---------------------------------------------------------------- register-resident MFMA GEMM
template <typename AT, int K, int KPAD, int NI, int MI, int NOUT, bool BIAS, bool F32OUT>
__device__ __forceinline__
void gemm_body(const AT* __restrict__ X,
               const __half* __restrict__ Wh, const __half* __restrict__ Wl,
               const float* __restrict__ bias, void* __restrict__ Cout,
               int M, int orow0, int vb) {
    constexpr int KS = KPAD / 32;
    constexpr int CSPLIT = NOUT / (16 * MI);
    const int tid  = threadIdx.x;
    const int wid  = tid >> 6, lane = tid & 63;
    const int lm   = lane & 15, q = lane >> 4;
    const int gw   = vb * 4 + wid;
    const int tile = gw / CSPLIT;
    const int c0   = (gw % CSPLIT) * (MI * 16);
    const int NT   = (M + NI * 16 - 1) / (NI * 16);
    if (tile >= NT) return;
    const int n0 = tile * (NI * 16);

    half8 wh[MI][KS], wl[MI][KS];
#pragma unroll
    for (int mi = 0; mi < MI; mi++)
#pragma unroll
        for (int ks = 0; ks < KS; ks++) {
            const size_t b = (size_t)(c0 + mi * 16 + lm) * KPAD + ks * 32 + q * 8;
            wh[mi][ks] = *(const half8*)&Wh[b];
            wl[mi][ks] = *(const half8*)&Wl[b];
        }

    f32x4 acc[NI][MI];
#pragma unroll
    for (int ni = 0; ni < NI; ni++)
#pragma unroll
        for (int mi = 0; mi < MI; mi++) acc[ni][mi] = (f32x4)0.0f;

#pragma unroll
    for (int ni = 0; ni < NI; ni++) {
        const int node = n0 + ni * 16 + lm;
        half8 xf[KS];
        if (node < M) {
#pragma unroll
            for (int ks = 0; ks < KS; ks++)
                xf[ks] = *(const half8*)((const __half*)X + (size_t)node * KPAD + ks * 32 + q * 8);
        } else {
#pragma unroll
            for (int ks = 0; ks < KS; ks++)
#pragma unroll
                for (int j = 0; j < 8; j++) xf[ks][j] = (_Float16)0.0f;
        }
#pragma unroll
        for (int ks = 0; ks < KS; ks++)
#pragma unroll
            for (int mi = 0; mi < MI; mi++) {
                acc[ni][mi] = __builtin_amdgcn_mfma_f32_16x16x32_f16(wh[mi][ks], xf[ks], acc[ni][mi], 0, 0, 0);
                acc[ni][mi] = __builtin_amdgcn_mfma_f32_16x16x32_f16(wl[mi][ks], xf[ks], acc[ni][mi], 0, 0, 0);
            }
    }

#pragma unroll
    for (int ni = 0; ni < NI; ni++) {
        const int node = n0 + ni * 16 + lm;
        if (node >= M) continue;
#pragma unroll
        for (int mi = 0; mi < MI; mi++) {
            const int cb = c0 + mi * 16 + q * 4;
            float4 bv = BIAS ? *(const float4*)&bias[cb] : make_float4(0.f, 0.f, 0.f, 0.f);
            float v0 = fmaf(acc[ni][mi][0], 0.0625f, bv.x);
            float v1 = fmaf(acc[ni][mi][1], 0.0625f, bv.y);
            float v2 = fmaf(acc[ni][mi][2], 0.0625f, bv.z);
            float v3 = fmaf(acc[ni][mi][3], 0.0625f, bv.w);
            if constexpr (F32OUT) {
                *(float4*)((float*)Cout + (size_t)(orow0 + node) * NOUT + cb) =
                    make_float4(v0, v1, v2, v3);
            } else {
                __half2 h0 = __floats2half2_rn(v0, v1);
                __half2 h1 = __floats2half2_rn(v2, v3);
                uint2 o; o.x = *(unsigned*)&h0; o.y = *(unsigned*)&h1;
                *(uint2*)((__half*)Cout + (size_t)(orow0 + node) * NOUT + cb) = o;
            }
        }
    }
}

template <typename AT, int K, int KPAD, int NI, int MI, int NOUT, bool BIAS, bool F32OUT>
__launch_bounds__(256)
__global__ void k_gemm_reg(const AT* __restrict__ X,
                           const __half* __restrict__ Wh, const __half* __restrict__ Wl,
                           const float* __restrict__ bias, void* __restrict__ Cout,
                           int M, int orow0) {
    gemm_body<AT, K, KPAD, NI, MI, NOUT, BIAS, F32OUT>(X, Wh, Wl, bias, Cout, M, orow0, blockIdx.x);
}

// ---------------------------------------------------------------- fill + LAYER-1 gemm (composed)
// g1 = x0@W1 via composed weights, NI=4 for 2x the independent load->MFMA
// chains per wave (R4 lesson; matches the hidden gemms' proven config).
// blocks [0,391): user g1; [391,1173): prod g1; [1173,+2344): CSR fill
#define BLK_U 391
#define BLK_P 782
#define BLK_F 2344
__launch_bounds__(256)
__global__ void k_fill_g1(const int* __restrict__ src, const int* __restrict__ dst,
                          const int* __restrict__ offs, const int* __restrict__ bsums,
                          const int* __restrict__ rank, const float* __restrict__ dinv,
                          int2* __restrict__ epack,
                          const __half* __restrict__ xU, const __half* __restrict__ xP,
                          const __half* __restrict__ whU1, const __half* __restrict__ wlU1,
                          const __half* __restrict__ whP1, const __half* __restrict__ wlP1,
                          const float* __restrict__ bu1, const float* __restrict__ bp1,
                          void* __restrict__ xB) {
    const int b = blockIdx.x;
    if (b < BLK_U) {
        gemm_body<__half,  64,  64, 4, 4, 128, true, false>(xU, whU1, wlU1, bu1, xB, NU, 0, b);
    } else if (b < BLK_U + BLK_P) {
        gemm_body<__half, 128, 128, 4, 2, 128, true, false>(xP, whP1, wlP1, bp1, xB, NP, NU, b - BLK_U);
    } else {
        int e = (b - BLK_U - BLK_P) * 256 + threadIdx.x;
        if (e < NE) {
            int s = src[e], d = dst[e];
            int p = offs[d] + bsums[d >> 10] + rank[e];
            int2 r;
            r.x = s;
            r.y = __float_as_int(dinv[s] * dinv[d]);
            epack[p] = r;
        }
    }
}

// ---------------------------------------------------------------- CSR gather + bias + ReLU
// (R10-measured: full 256B rows, 8B lanes, 2 rows/gather-instr, dead tail
// slots clamped to the L1-hot self row.)
__launch_bounds__(256)
__global__ void k_aggregate(const __half* __restrict__ y, const int* __restrict__ offs,
                            const int* __restrict__ bsums, const int2* __restrict__ epack,
                            const float* __restrict__ dinv, const float* __restrict__ bias,
                            __half* __restrict__ out) {
    const int node = __builtin_amdgcn_readfirstlane(blockIdx.x * 4 + (threadIdx.x >> 6));
    const int l = threadIdx.x & 63;
    const int h = l >> 5, j = l & 31;

    int e0 = offs[node] + bsums[node >> 10];
    int e1 = (node + 1 < NN) ? (offs[node + 1] + bsums[(node + 1) >> 10]) : NE;
    e0 = __builtin_amdgcn_readfirstlane(e0);
    e1 = __builtin_amdgcn_readfirstlane(e1);

    const h4v* y4 = (const h4v*)y;               // row stride = 32 (8B units)

    const float di2 = dinv[node] * dinv[node];
    h4v sv = y4[(size_t)node * 32 + j];
    float4 bv = *(const float4*)&bias[4 * j];

    f32x4 acc0 = (f32x4)0.f, acc1 = (f32x4)0.f, acc2 = (f32x4)0.f, acc3 = (f32x4)0.f;

    for (int e = e0; e < e1; e += 8) {
        const int eb = e + 4 * h;
        const int2* pe = epack + eb;
        int2 p0 = pe[0];                          // contiguous 32B per half
        int2 p1 = pe[1];
        int2 p2 = pe[2];
        int2 p3 = pe[3];
        const bool k0 = (eb + 0 < e1), k1 = (eb + 1 < e1);
        const bool k2 = (eb + 2 < e1), k3 = (eb + 3 < e1);
        float w0 = k0 ? __int_as_float(p0.y) : 0.f;
        float w1 = k1 ? __int_as_float(p1.y) : 0.f;
        float w2 = k2 ? __int_as_float(p2.y) : 0.f;
        float w3 = k3 ? __int_as_float(p3.y) : 0.f;
        const int s0 = k0 ? p0.x : node;          // dead slot -> self row (L1-hot)
        const int s1 = k1 ? p1.x : node;
        const int s2 = k2 ? p2.x : node;
        const int s3 = k3 ? p3.x : node;
        h4v v0 = y4[(size_t)s0 * 32 + j];         // 2 full rows per gather instr
        h4v v1 = y4[(size_t)s1 * 32 + j];
        h4v v2 = y4[(size_t)s2 * 32 + j];
        h4v v3 = y4[(size_t)s3 * 32 + j];
        acc0[0] = fmaf((float)v0[0], w0, acc0[0]); acc0[1] = fmaf((float)v0[1], w0, acc0[1]);
        acc0[2] = fmaf((float)v0[2], w0, acc0[2]); acc0[3] = fmaf((float)v0[3], w0, acc0[3]);
        acc1[0] = fmaf((float)v1[0], w1, acc1[0]); acc1[1] = fmaf((float)v1[1], w1, acc1[1]);
        acc1[2] = fmaf((float)v1[2], w1, acc1[2]); acc1[3] = fmaf((float)v1[3], w1, acc1[3]);
        acc2[0] = fmaf((float)v2[0], w2, acc2[0]); acc2[1] = fmaf((float)v2[1], w2, acc2[1]);
        acc2[2] = fmaf((float)v2[2], w2, acc2[2]); acc2[3] = fmaf((float)v2[3], w2, acc2[3]);
        acc3[0] = fmaf((float)v3[0], w3, acc3[0]); acc3[1] = fmaf((float)v3[1], w3, acc3[1]);
        acc3[2] = fmaf((float)v3[2], w3, acc3[2]); acc3[3] = fmaf((float)v3[3], w3, acc3[3]);
    }

    f32x4 s = (acc0 + acc1) + (acc2 + acc3);
    float t0 = s[0] + __shfl_xor(s[0], 32, 64);
    float t1 = s[1] + __shfl_xor(s[1], 32, 64);
    float t2 = s[2] + __shfl_xor(s[2], 32, 64);
    float t3 = s[3] + __shfl_xor(s[3], 32, 64);

    float r0 = fmaf((float)sv[0], di2, t0) + bv.x;
    float r1 = fmaf((float)sv[1], di2, t1) + bv.y;
    float r2 = fmaf((float)sv[2], di2, t2) + bv.z;
    float r3 = fmaf((float)sv[3], di2, t3) + bv.w;
    if (l < 32) {
        __half2 ha = __floats2half2_rn(fmaxf(r0, 0.f), fmaxf(r1, 0.f));
        __half2 hb = __floats2half2_rn(fmaxf(r2, 0.f), fmaxf(r3, 0.f));
        uint2 o; o.x = *(unsigned*)&ha; o.y = *(unsigned*)&hb;
        *(uint2*)(out + (size_t)node * H + 4 * j) = o;
    }
}

// ---------------------------------------------------------------- launch
extern "C" void kernel_launch(void* const* d_in, const int* in_sizes, int n_in,
                              void* d_out, int out_size, void* d_ws, size_t ws_size,
                              hipStream_t stream) {
    const float* user = (const float*)d_in[0];
    const float* prod = (const float*)d_in[1];
    const int*   eidx = (const int*)  d_in[2];
    const int*   edst = eidx + NE;
    const int*   esrc = eidx;
    const float* Wu = (const float*)d_in[3];
    const float* bu = (const float*)d_in[4];
    const float* Wp = (const float*)d_in[5];
    const float* bp = (const float*)d_in[6];
    const float* W1 = (const float*)d_in[7];
    const float* b1 = (const float*)d_in[8];
    const float* W2 = (const float*)d_in[9];
    const float* b2 = (const float*)d_in[10];
    const float* W3 = (const float*)d_in[11];
    const float* b3 = (const float*)d_in[12];
    const float* Wo = (const float*)d_in[13];
    const float* bo = (const float*)d_in[14];
    float* out = (float*)d_out;

    char* ws = (char*)d_ws;
    size_t p = 0;
    auto alloc = [&](size_t bytes) -> void* {
        void* r = ws + p;
        p += (bytes + 255) & ~(size_t)255;
        return r;
    };
    __half* xA   = (__half*)alloc((size_t)NN * H * 2);
    __half* xB   = (__half*)alloc((size_t)NN * H * 2);
    __half* xU   = (__half*)alloc((size_t)NU * 64 * 2);
    __half* xP   = (__half*)alloc((size_t)NP * 128 * 2);
    int*   cnt   = (int*)  alloc((size_t)NN * 4);
    int*   rank  = (int*)  alloc((size_t)NE * 4);
    int*   offs  = (int*)  alloc((size_t)(NN + 1) * 4);
    float* dinv  = (float*)alloc((size_t)NN * 4);
    int2*  epack = (int2*) alloc((size_t)(NE + 8) * 8);
    int*   bsums = (int*)  alloc(128 * 4);
    __half* whU1 = (__half*)alloc(128 * 64 * 2);
    __half* wlU1 = (__half*)alloc(128 * 64 * 2);
    __half* whP1 = (__half*)alloc(128 * 128 * 2);
    __half* wlP1 = (__half*)alloc(128 * 128 * 2);
    __half* wh2 = (__half*)alloc(128 * 128 * 2);
    __half* wl2 = (__half*)alloc(128 * 128 * 2);
    __half* wh3 = (__half*)alloc(128 * 128 * 2);
    __half* wl3 = (__half*)alloc(128 * 128 * 2);
    __half* whO = (__half*)alloc(16 * 128 * 2);
    __half* wlO = (__half*)alloc(16 * 128 * 2);
    float* bu1  = (float*)alloc(128 * 4);
    float* bp1  = (float*)alloc(128 * 4);

    const int NBLK = (NN + SCAN_CHUNK - 1) / SCAN_CHUNK;   // 98

    // zero cnt, then prep (composed weights + conversions + count+rank tail)
    hipMemsetAsync(cnt, 0, (size_t)NN * 4, stream);
    {
        const int total = 2459656 + NE;                    // 3,059,656
        k_prep<<<(total + 255) / 256, 256, 0, stream>>>(
            Wu, Wp, W1, W2, W3, Wo, user, prod, bu, bp, edst,
            whU1, wlU1, whP1, wlP1, wh2, wl2, wh3, wl3, whO, wlO,
            bu1, bp1, xU, xP, cnt, rank, epack);
    }

    // graph structure
    k_scan1<<<NBLK, SCAN_TPB, 0, stream>>>(cnt, offs, bsums, dinv, NN);
    k_scan2<<<1, 128, 0, stream>>>(bsums, NBLK);

    // CSR fill + layer-1 gemm (composed weights) -> xB, one launch
    k_fill_g1<<<BLK_U + BLK_P + BLK_F, 256, 0, stream>>>(
        esrc, edst, offs, bsums, rank, dinv, epack,
        xU, xP, whU1, wlU1, whP1, wlP1, bu1, bp1, xB);

    const int blkG = (1563 * 2 + 3) / 4;   // 782
    const int blkO = (1563 + 3) / 4;       // 391

    // layer 1 aggregate
    k_aggregate<<<NN / 4, 256, 0, stream>>>(xB, offs, bsums, epack, dinv, b1, xA);
    // layer 2
    k_gemm_reg<__half, 128, 128, 4, 4, 128, false, false><<<blkG, 256, 0, stream>>>(xA, wh2, wl2, nullptr, xB, NN, 0);
    k_aggregate<<<NN / 4, 256, 0, stream>>>(xB, offs, bsums, epack, dinv, b2, xA);
    // layer 3
    k_gemm_reg<__half, 128, 128, 4, 4, 128, false, false><<<blkG, 256, 0, stream>>>(xA, wh3, wl3, nullptr, xB, NN, 0);
    k_aggregate<<<NN / 4, 256, 0, stream>>>(xB, offs, bsums, epack, dinv, b3, xA);

    // output head [NN,128] @ [128,16] + bo -> fp32 out
    k_gemm_reg<__half, 128, 128, 4, 1, 16, true, true><<<blkO, 256, 0, stream>>>(xA, whO, wlO, bo, out, NN, 0);
}

// Round 14
// 255.281 us; speedup vs baseline: 1.2011x; 1.0085x over previous
//
#include <hip/hip_runtime.h>
#include <hip/hip_fp16.h>

#define NU 50000
#define NP 50000
#define NN 100000
#define NE 600000
#define H  128
#define O  16

typedef __attribute__((ext_vector_type(8))) _Float16 half8;
typedef __attribute__((ext_vector_type(4))) _Float16 h4v;
typedef __attribute__((ext_vector_type(4))) float f32x4;

// ---------------------------------------------------------------- fused prep
// Layer-1 composed into input weights: Wu1 = Wu@W1, bu1 = bu@W1 (fp32-exact).
// cnt zeroed by hipMemsetAsync before this kernel; degree-count atomics folded
// in as the tail range. Ranges as R12.
__global__ void k_prep(const float* __restrict__ Wu, const float* __restrict__ Wp,
                       const float* __restrict__ W1, const float* __restrict__ W2,
                       const float* __restrict__ W3, const float* __restrict__ Wo,
                       const float* __restrict__ user, const float* __restrict__ prod,
                       const float* __restrict__ bu, const float* __restrict__ bp,
                       const int* __restrict__ edst,
                       __half* __restrict__ whU1, __half* __restrict__ wlU1,
                       __half* __restrict__ whP1, __half* __restrict__ wlP1,
                       __half* __restrict__ wh2, __half* __restrict__ wl2,
                       __half* __restrict__ wh3, __half* __restrict__ wl3,
                       __half* __restrict__ whO, __half* __restrict__ wlO,
                       float* __restrict__ bu1, float* __restrict__ bp1,
                       __half* __restrict__ xU, __half* __restrict__ xP,
                       int* __restrict__ cnt, int* __restrict__ rank,
                       int2* __restrict__ epack) {
    int idx = blockIdx.x * blockDim.x + threadIdx.x;
    if (idx >= 2459656) {                      // degree count + rank
        int e = idx - 2459656;
        if (e < NE) rank[e] = atomicAdd(&cnt[edst[e]], 1);
        return;
    }
    if (idx >= 859656) {                       // prod conversion
        int q = idx - 859656;
        int row = q >> 5, kq = (q & 31) * 4;
        float4 v;
        if (kq < 100) v = *(const float4*)(prod + row * 100 + kq);
        else { v.x = 0.f; v.y = 0.f; v.z = 0.f; v.w = 0.f; }
        __half2 a = __floats2half2_rn(v.x, v.y);
        __half2 b = __floats2half2_rn(v.z, v.w);
        uint2 o; o.x = *(unsigned*)&a; o.y = *(unsigned*)&b;
        *(uint2*)(xP + (size_t)row * 128 + kq) = o;
        return;
    }
    if (idx >= 59656) {                        // user conversion
        int e = (idx - 59656) * 4;
        float4 v = *(const float4*)(user + e);
        __half2 a = __floats2half2_rn(v.x, v.y);
        __half2 b = __floats2half2_rn(v.z, v.w);
        uint2 o; o.x = *(unsigned*)&a; o.y = *(unsigned*)&b;
        *(uint2*)(xU + e) = o;
        return;
    }
    if (idx >= 59648) {                        // epack pad
        int2 z; z.x = 0; z.y = 0;
        epack[NE + (idx - 59648)] = z;
        return;
    }
    if (idx >= 59392) {                        // composed biases (fp32)
        int n = idx - 59392;
        const float* bsrc = (n < 128) ? bu : bp;
        int nn = n & 127;
        float acc = 0.f;
        for (int j = 0; j < 128; ++j) acc = fmaf(bsrc[j], W1[j * 128 + nn], acc);
        if (n < 128) bu1[nn] = acc; else bp1[nn] = acc;
        return;
    }
    // weight decompositions
    float x;
    __half *Wh, *Wl; int sidx;
    if (idx < 8192) {                          // Wu1 = Wu@W1, [64][128] KPAD=64
        int n = idx >> 6, k = idx & 63;
        float acc = 0.f;
        for (int j = 0; j < 128; ++j) acc = fmaf(Wu[k * 128 + j], W1[j * 128 + n], acc);
        x = acc * 16.0f; Wh = whU1; Wl = wlU1; sidx = idx;
    } else if (idx < 24576) {                  // Wp1 = Wp@W1, [100->128][128]
        int l = idx - 8192;
        int n = l >> 7, k = l & 127;
        float acc = 0.f;
        if (k < 100)
            for (int j = 0; j < 128; ++j) acc = fmaf(Wp[k * 128 + j], W1[j * 128 + n], acc);
        x = acc * 16.0f; Wh = whP1; Wl = wlP1; sidx = l;
    } else if (idx < 40960) {                  // W2
        int l = idx - 24576;
        int n = l >> 7, k = l & 127;
        x = W2[k * 128 + n] * 16.0f; Wh = wh2; Wl = wl2; sidx = l;
    } else if (idx < 57344) {                  // W3
        int l = idx - 40960;
        int n = l >> 7, k = l & 127;
        x = W3[k * 128 + n] * 16.0f; Wh = wh3; Wl = wl3; sidx = l;
    } else {                                   // Wo [128][16]
        int l = idx - 57344;
        int n = l >> 7, k = l & 127;
        x = Wo[k * 16 + n] * 16.0f; Wh = whO; Wl = wlO; sidx = l;
    }
    __half h = __float2half_rn(x);
    __half l2 = __float2half_rn(x - __half2float(h));
    Wh[sidx] = h; Wl[sidx] = l2;
}

// ---------------------------------------------------------------- exclusive scan
#define SCAN_TPB 256
#define SCAN_VPT 4
#define SCAN_CHUNK (SCAN_TPB * SCAN_VPT)   // 1024 -> consumers use >>10

__global__ void k_scan1(const int* __restrict__ in, int* __restrict__ out,
                        int* __restrict__ bsums, float* __restrict__ dinv, int n) {
    __shared__ int sh[SCAN_TPB];
    int t = threadIdx.x, b = blockIdx.x;
    int base = b * SCAN_CHUNK + t * SCAN_VPT;
    int v[SCAN_VPT]; int s = 0;
#pragma unroll
    for (int i = 0; i < SCAN_VPT; i++) {
        int idx = base + i;
        v[i] = (idx < n) ? in[idx] : 0;
        if (idx < n) dinv[idx] = rsqrtf((float)(v[i] + 1));
        s += v[i];
    }
    sh[t] = s; __syncthreads();
    for (int off = 1; off < SCAN_TPB; off <<= 1) {
        int x = (t >= off) ? sh[t - off] : 0;
        __syncthreads();
        sh[t] += x;
        __syncthreads();
    }
    int run = (t > 0) ? sh[t - 1] : 0;
    if (t == SCAN_TPB - 1) bsums[b] = sh[t];
#pragma unroll
    for (int i = 0; i < SCAN_VPT; i++) {
        int idx = base + i;
        if (idx < n) out[idx] = run;
        run += v[i];
    }
}

__global__ void k_scan2(int* __restrict__ bsums, int nb) {
    __shared__ int sh[128];
    int t = threadIdx.x;
    int v = (t < nb) ? bsums[t] : 0;
    sh[t] = v; __syncthreads();
    for (int off = 1; off < 128; off <<= 1) {
        int x = (t >= off) ? sh[t - off] : 0;
        __syncthreads();
        sh[t] += x;
        __syncthreads();
    }
    if (t < nb) bsums[t] = sh[t] - v;
}

// ---------------------------------------------------------------- register-resident MFMA GEMM
template <typename AT, int K, int KPAD, int NI, int MI, int NOUT, bool BIAS, bool F32OUT>
__device__ __forceinline__
void gemm_body(const AT* __restrict__ X,
               const __half* __restrict__ Wh, const __half* __restrict__ Wl,
               const float* __restrict__ bias, void* __restrict__ Cout,
               int M, int orow0, int vb) {
    constexpr int KS = KPAD / 32;
    constexpr int CSPLIT = NOUT / (16 * MI);
    const int tid  = threadIdx.x;
    const int wid  = tid >> 6, lane = tid & 63;
    const int lm   = lane & 15, q = lane >> 4;
    const int gw   = vb * 4 + wid;
    const int tile = gw / CSPLIT;
    const int c0   = (gw % CSPLIT) * (MI * 16);
    const int NT   = (M + NI * 16 - 1) / (NI * 16);
    if (tile >= NT) return;
    const int n0 = tile * (NI * 16);

    half8 wh[MI][KS], wl[MI][KS];
#pragma unroll
    for (int mi = 0; mi < MI; mi++)
#pragma unroll
        for (int ks = 0; ks < KS; ks++) {
            const size_t b = (size_t)(c0 + mi * 16 + lm) * KPAD + ks * 32 + q * 8;
            wh[mi][ks] = *(const half8*)&Wh[b];
            wl[mi][ks] = *(const half8*)&Wl[b];
        }

    f32x4 acc[NI][MI];
#pragma unroll
    for (int ni = 0; ni < NI; ni++)
#pragma unroll
        for (int mi = 0; mi < MI; mi++) acc[ni][mi] = (f32x4)0.0f;

#pragma unroll
    for (int ni = 0; ni < NI; ni++) {
        const int node = n0 + ni * 16 + lm;
        half8 xf[KS];
        if (node < M) {
#pragma unroll
            for (int ks = 0; ks < KS; ks++)
                xf[ks] = *(const half8*)((const __half*)X + (size_t)node * KPAD + ks * 32 + q * 8);
        } else {
#pragma unroll
            for (int ks = 0; ks < KS; ks++)
#pragma unroll
                for (int j = 0; j < 8; j++) xf[ks][j] = (_Float16)0.0f;
        }
#pragma unroll
        for (int ks = 0; ks < KS; ks++)
#pragma unroll
            for (int mi = 0; mi < MI; mi++) {
                acc[ni][mi] = __builtin_amdgcn_mfma_f32_16x16x32_f16(wh[mi][ks], xf[ks], acc[ni][mi], 0, 0, 0);
                acc[ni][mi] = __builtin_amdgcn_mfma_f32_16x16x32_f16(wl[mi][ks], xf[ks], acc[ni][mi], 0, 0, 0);
            }
    }

#pragma unroll
    for (int ni = 0; ni < NI; ni++) {
        const int node = n0 + ni * 16 + lm;
        if (node >= M) continue;
#pragma unroll
        for (int mi = 0; mi < MI; mi++) {
            const int cb = c0 + mi * 16 + q * 4;
            float4 bv = BIAS ? *(const float4*)&bias[cb] : make_float4(0.f, 0.f, 0.f, 0.f);
            float v0 = fmaf(acc[ni][mi][0], 0.0625f, bv.x);
            float v1 = fmaf(acc[ni][mi][1], 0.0625f, bv.y);
            float v2 = fmaf(acc[ni][mi][2], 0.0625f, bv.z);
            float v3 = fmaf(acc[ni][mi][3], 0.0625f, bv.w);
            if constexpr (F32OUT) {
                *(float4*)((float*)Cout + (size_t)(orow0 + node) * NOUT + cb) =
                    make_float4(v0, v1, v2, v3);
            } else {
                __half2 h0 = __floats2half2_rn(v0, v1);
                __half2 h1 = __floats2half2_rn(v2, v3);
                uint2 o; o.x = *(unsigned*)&h0; o.y = *(unsigned*)&h1;
                *(uint2*)((__half*)Cout + (size_t)(orow0 + node) * NOUT + cb) = o;
            }
        }
    }
}

template <typename AT, int K, int KPAD, int NI, int MI, int NOUT, bool BIAS, bool F32OUT>
__launch_bounds__(256)
__global__ void k_gemm_reg(const AT* __restrict__ X,
                           const __half* __restrict__ Wh, const __half* __restrict__ Wl,
                           const float* __restrict__ bias, void* __restrict__ Cout,
                           int M, int orow0) {
    gemm_body<AT, K, KPAD, NI, MI, NOUT, BIAS, F32OUT>(X, Wh, Wl, bias, Cout, M, orow0, blockIdx.x);
}

// ---------------------------------------------------------------- fill + LAYER-1 gemm + final offsets
// blocks [0,391): user g1; [391,1173): prod g1; [1173,3517): CSR fill;
// [3517,3908): eoffs[i] = offs[i] + bsums[i>>10] (finalized CSR offsets,
// removes a dependent scalar load + branch from every aggregate wave)
#define BLK_U 391
#define BLK_P 782
#define BLK_F 2344
#define BLK_E 391
__launch_bounds__(256)
__global__ void k_fill_g1(const int* __restrict__ src, const int* __restrict__ dst,
                          const int* __restrict__ offs, const int* __restrict__ bsums,
                          const int* __restrict__ rank, const float* __restrict__ dinv,
                          int2* __restrict__ epack, int* __restrict__ eoffs,
                          const __half* __restrict__ xU, const __half* __restrict__ xP,
                          const __half* __restrict__ whU1, const __half* __restrict__ wlU1,
                          const __half* __restrict__ whP1, const __half* __restrict__ wlP1,
                          const float* __restrict__ bu1, const float* __restrict__ bp1,
                          void* __restrict__ xB) {
    const int b = blockIdx.x;
    if (b < BLK_U) {
        gemm_body<__half,  64,  64, 4, 4, 128, true, false>(xU, whU1, wlU1, bu1, xB, NU, 0, b);
    } else if (b < BLK_U + BLK_P) {
        gemm_body<__half, 128, 128, 4, 2, 128, true, false>(xP, whP1, wlP1, bp1, xB, NP, NU, b - BLK_U);
    } else if (b < BLK_U + BLK_P + BLK_F) {
        int e = (b - BLK_U - BLK_P) * 256 + threadIdx.x;
        if (e < NE) {
            int s = src[e], d = dst[e];
            int p = offs[d] + bsums[d >> 10] + rank[e];
            int2 r;
            r.x = s;
            r.y = __float_as_int(dinv[s] * dinv[d]);
            epack[p] = r;
        }
    } else {
        int i = (b - BLK_U - BLK_P - BLK_F) * 256 + threadIdx.x;
        if (i < NN) eoffs[i] = offs[i] + bsums[i >> 10];
        else if (i == NN) eoffs[NN] = NE;
    }
}

// ---------------------------------------------------------------- CSR gather + bias + ReLU
// 16B lanes: lane = (quarter qq = l>>4, jj = l&15); 16 lanes x 16B cover a full
// 256B row -> ONE gather instruction fetches FOUR random rows (R8 fetched 2).
// Same traffic, half the gather-issue count. Batch of 8 edges = 2 gathers
// (slots e+qq, e+4+qq). Dead slots clamp to the L1-hot self row (R10 fix).
// Quarter-reduce = 2 shfl_xor levels (16, 32).
__launch_bounds__(256)
__global__ void k_aggregate(const __half* __restrict__ y, const int* __restrict__ eoffs,
                            const int2* __restrict__ epack,
                            const float* __restrict__ dinv, const float* __restrict__ bias,
                            __half* __restrict__ out) {
    const int node = __builtin_amdgcn_readfirstlane(blockIdx.x * 4 + (threadIdx.x >> 6));
    const int l  = threadIdx.x & 63;
    const int qq = l >> 4, jj = l & 15;

    const int e0 = __builtin_amdgcn_readfirstlane(eoffs[node]);
    const int e1 = __builtin_amdgcn_readfirstlane(eoffs[node + 1]);

    const half8* y8 = (const half8*)y;           // row stride = 16 half8 (16B) units
    const float di2 = dinv[node] * dinv[node];

    // self row + bias: only quarter 0 needs them (exec-masked 256B load)
    half8 sv;
    float4 bv0, bv1;
    if (qq == 0) {
        sv  = y8[(size_t)node * 16 + jj];
        bv0 = *(const float4*)&bias[8 * jj];
        bv1 = *(const float4*)&bias[8 * jj + 4];
    }

    f32x4 a0l = (f32x4)0.f, a0h = (f32x4)0.f;    // slot-chain 0 (edges e+qq)
    f32x4 a1l = (f32x4)0.f, a1h = (f32x4)0.f;    // slot-chain 1 (edges e+4+qq)

    for (int e = e0; e < e1; e += 8) {
        const int i0 = e + qq;                   // epack padded by 8 zero entries
        const int i1 = e + 4 + qq;
        int2 p0 = epack[i0];
        int2 p1 = epack[i1];
        const bool k0 = (i0 < e1), k1 = (i1 < e1);
        float w0 = k0 ? __int_as_float(p0.y) : 0.f;
        float w1 = k1 ? __int_as_float(p1.y) : 0.f;
        const int s0 = k0 ? p0.x : node;         // dead slot -> self row (L1-hot)
        const int s1 = k1 ? p1.x : node;
        half8 v0 = y8[(size_t)s0 * 16 + jj];     // 4 full rows per gather instr
        half8 v1 = y8[(size_t)s1 * 16 + jj];
        a0l[0] = fmaf((float)v0[0], w0, a0l[0]); a0l[1] = fmaf((float)v0[1], w0, a0l[1]);
        a0l[2] = fmaf((float)v0[2], w0, a0l[2]); a0l[3] = fmaf((float)v0[3], w0, a0l[3]);
        a0h[0] = fmaf((float)v0[4], w0, a0h[0]); a0h[1] = fmaf((float)v0[5], w0, a0h[1]);
        a0h[2] = fmaf((float)v0[6], w0, a0h[2]); a0h[3] = fmaf((float)v0[7], w0, a0h[3]);
        a1l[0] = fmaf((float)v1[0], w1, a1l[0]); a1l[1] = fmaf((float)v1[1], w1, a1l[1]);
        a1l[2] = fmaf((float)v1[2], w1, a1l[2]); a1l[3] = fmaf((float)v1[3], w1, a1l[3]);
        a1h[0] = fmaf((float)v1[4], w1, a1h[0]); a1h[1] = fmaf((float)v1[5], w1, a1h[1]);
        a1h[2] = fmaf((float)v1[6], w1, a1h[2]); a1h[3] = fmaf((float)v1[7], w1, a1h[3]);
    }

    f32x4 sl = a0l + a1l;
    f32x4 sh = a0h + a1h;
#pragma unroll
    for (int m = 16; m <= 32; m <<= 1) {
        sl[0] += __shfl_xor(sl[0], m, 64); sl[1] += __shfl_xor(sl[1], m, 64);
        sl[2] += __shfl_xor(sl[2], m, 64); sl[3] += __shfl_xor(sl[3], m, 64);
        sh[0] += __shfl_xor(sh[0], m, 64); sh[1] += __shfl_xor(sh[1], m, 64);
        sh[2] += __shfl_xor(sh[2], m, 64); sh[3] += __shfl_xor(sh[3], m, 64);
    }

    if (qq == 0) {
        float r0 = fmaf((float)sv[0], di2, sl[0]) + bv0.x;
        float r1 = fmaf((float)sv[1], di2, sl[1]) + bv0.y;
        float r2 = fmaf((float)sv[2], di2, sl[2]) + bv0.z;
        float r3 = fmaf((float)sv[3], di2, sl[3]) + bv0.w;
        float r4 = fmaf((float)sv[4], di2, sh[0]) + bv1.x;
        float r5 = fmaf((float)sv[5], di2, sh[1]) + bv1.y;
        float r6 = fmaf((float)sv[6], di2, sh[2]) + bv1.z;
        float r7 = fmaf((float)sv[7], di2, sh[3]) + bv1.w;
        __half2 h0 = __floats2half2_rn(fmaxf(r0, 0.f), fmaxf(r1, 0.f));
        __half2 h1 = __floats2half2_rn(fmaxf(r2, 0.f), fmaxf(r3, 0.f));
        __half2 h2 = __floats2half2_rn(fmaxf(r4, 0.f), fmaxf(r5, 0.f));
        __half2 h3 = __floats2half2_rn(fmaxf(r6, 0.f), fmaxf(r7, 0.f));
        uint4 o;
        o.x = *(unsigned*)&h0; o.y = *(unsigned*)&h1;
        o.z = *(unsigned*)&h2; o.w = *(unsigned*)&h3;
        *(uint4*)(out + (size_t)node * H + 8 * jj) = o;
    }
}

// ---------------------------------------------------------------- launch
extern "C" void kernel_launch(void* const* d_in, const int* in_sizes, int n_in,
                              void* d_out, int out_size, void* d_ws, size_t ws_size,
                              hipStream_t stream) {
    const float* user = (const float*)d_in[0];
    const float* prod = (const float*)d_in[1];
    const int*   eidx = (const int*)  d_in[2];
    const int*   edst = eidx + NE;
    const int*   esrc = eidx;
    const float* Wu = (const float*)d_in[3];
    const float* bu = (const float*)d_in[4];
    const float* Wp = (const float*)d_in[5];
    const float* bp = (const float*)d_in[6];
    const float* W1 = (const float*)d_in[7];
    const float* b1 = (const float*)d_in[8];
    const float* W2 = (const float*)d_in[9];
    const float* b2 = (const float*)d_in[10];
    const float* W3 = (const float*)d_in[11];
    const float* b3 = (const float*)d_in[12];
    const float* Wo = (const float*)d_in[13];
    const float* bo = (const float*)d_in[14];
    float* out = (float*)d_out;

    char* ws = (char*)d_ws;
    size_t p = 0;
    auto alloc = [&](size_t bytes) -> void* {
        void* r = ws + p;
        p += (bytes + 255) & ~(size_t)255;
        return r;
    };
    __half* xA   = (__half*)alloc((size_t)NN * H * 2);
    __half* xB   = (__half*)alloc((size_t)NN * H * 2);
    __half* xU   = (__half*)alloc((size_t)NU * 64 * 2);
    __half* xP   = (__half*)alloc((size_t)NP * 128 * 2);
    int*   cnt   = (int*)  alloc((size_t)NN * 4);
    int*   rank  = (int*)  alloc((size_t)NE * 4);
    int*   offs  = (int*)  alloc((size_t)(NN + 1) * 4);
    int*   eoffs = (int*)  alloc((size_t)(NN + 1) * 4);
    float* dinv  = (float*)alloc((size_t)NN * 4);
    int2*  epack = (int2*) alloc((size_t)(NE + 8) * 8);
    int*   bsums = (int*)  alloc(128 * 4);
    __half* whU1 = (__half*)alloc(128 * 64 * 2);
    __half* wlU1 = (__half*)alloc(128 * 64 * 2);
    __half* whP1 = (__half*)alloc(128 * 128 * 2);
    __half* wlP1 = (__half*)alloc(128 * 128 * 2);
    __half* wh2 = (__half*)alloc(128 * 128 * 2);
    __half* wl2 = (__half*)alloc(128 * 128 * 2);
    __half* wh3 = (__half*)alloc(128 * 128 * 2);
    __half* wl3 = (__half*)alloc(128 * 128 * 2);
    __half* whO = (__half*)alloc(16 * 128 * 2);
    __half* wlO = (__half*)alloc(16 * 128 * 2);
    float* bu1  = (float*)alloc(128 * 4);
    float* bp1  = (float*)alloc(128 * 4);

    const int NBLK = (NN + SCAN_CHUNK - 1) / SCAN_CHUNK;   // 98

    // zero cnt, then prep (composed weights + conversions + count+rank tail)
    hipMemsetAsync(cnt, 0, (size_t)NN * 4, stream);
    {
        const int total = 2459656 + NE;                    // 3,059,656
        k_prep<<<(total + 255) / 256, 256, 0, stream>>>(
            Wu, Wp, W1, W2, W3, Wo, user, prod, bu, bp, edst,
            whU1, wlU1, whP1, wlP1, wh2, wl2, wh3, wl3, whO, wlO,
            bu1, bp1, xU, xP, cnt, rank, epack);
    }

    // graph structure
    k_scan1<<<NBLK, SCAN_TPB, 0, stream>>>(cnt, offs, bsums, dinv, NN);
    k_scan2<<<1, 128, 0, stream>>>(bsums, NBLK);

    // CSR fill + layer-1 gemm (composed weights) + eoffs finalize, one launch
    k_fill_g1<<<BLK_U + BLK_P + BLK_F + BLK_E, 256, 0, stream>>>(
        esrc, edst, offs, bsums, rank, dinv, epack, eoffs,
        xU, xP, whU1, wlU1, whP1, wlP1, bu1, bp1, xB);

    const int blkG = (1563 * 2 + 3) / 4;   // 782
    const int blkO = (1563 + 3) / 4;       // 391

    // layer 1 aggregate
    k_aggregate<<<NN / 4, 256, 0, stream>>>(xB, eoffs, epack, dinv, b1, xA);
    // layer 2
    k_gemm_reg<__half, 128, 128, 4, 4, 128, false, false><<<blkG, 256, 0, stream>>>(xA, wh2, wl2, nullptr, xB, NN, 0);
    k_aggregate<<<NN / 4, 256, 0, stream>>>(xB, eoffs, epack, dinv, b2, xA);
    // layer 3
    k_gemm_reg<__half, 128, 128, 4, 4, 128, false, false><<<blkG, 256, 0, stream>>>(xA, wh3, wl3, nullptr, xB, NN, 0);
    k_aggregate<<<NN / 4, 256, 0, stream>>>(xB, eoffs, epack, dinv, b3, xA);

    // output head [NN,128] @ [128,16] + bo -> fp32 out
    k_gemm_reg<__half, 128, 128, 4, 1, 16, true, true><<<blkO, 256, 0, stream>>>(xA, whO, wlO, bo, out, NN, 0);
}